// Round 1
// baseline (446.072 us; speedup 1.0000x reference)
//
#include <hip/hip_runtime.h>
#include <stdint.h>

// MultiBoxLoss: B=64 rows, D=65536 anchors, ~2% positives.
// Key insight: the double-argsort hard-negative mining only needs, per row,
// the exact k-th largest bce_neg value (k = 3*num_pos) and the sum of the
// top-k values. Non-negative floats order like their uint bits -> 3-level
// radix select (12/12/8 bits) with per-row histograms. Ties at the threshold
// all share the same float value, so sum += ties*T is exact w.r.t. the
// reference's stable argsort semantics (threshold > 0 always for this data).

#define B_ 64
#define D_ 65536
#define NEGPOS 3
#define BPR 16                 // blocks per row for full-pass kernels
#define CHUNK (D_ / BPR)       // 4096 elements per block
#define GROUPS (CHUNK / 4)     // 1024 float4 groups per block
#define CAP 32768              // per-row candidate capacity (bin width ~12.5% rel)

// ---------------- ws layout (bytes) ----------------
// zeroed region (one hipMemsetAsync):
#define OFF_SL1      0                          // double: sum smooth_l1 over pos
#define OFF_BCEP     8                          // double: sum bce over pos
#define OFF_NUMPOS   16                         // int[64]
#define OFF_CANDCNT  272                        // u32[64]
#define OFF_NEGSUM   528                        // double[64]: selected-neg bce sum
#define OFF_HIST     1040                       // u32[64*4096] level-1 histograms
#define ZERO_BYTES   (1040 + 64 * 4096 * 4)     // 1,049,616
// non-zeroed:
#define OFF_J1       1049728                    // int[64]
#define OFF_REM1     1049984                    // int[64]
#define OFF_KK       1050240                    // int[64]
#define OFF_BCENEG   1050496                    // float[64*65536] (16-aligned)
#define OFF_CAND     (1050496 + 64 * 65536 * 4) // float[64*CAP]

__device__ __forceinline__ float bce_logits(float x, int t) {
    float ax = fabsf(x);
    float v = fmaxf(x, 0.0f) + log1pf(expf(-ax));
    if (t > 0) v -= x;
    return v;
}

__device__ __forceinline__ float smooth_l1_4(float4 a, float4 b) {
    float s = 0.0f, d, ad;
    d = a.x - b.x; ad = fabsf(d); s += (ad < 1.0f) ? 0.5f * d * d : ad - 0.5f;
    d = a.y - b.y; ad = fabsf(d); s += (ad < 1.0f) ? 0.5f * d * d : ad - 0.5f;
    d = a.z - b.z; ad = fabsf(d); s += (ad < 1.0f) ? 0.5f * d * d : ad - 0.5f;
    d = a.w - b.w; ad = fabsf(d); s += (ad < 1.0f) ? 0.5f * d * d : ad - 0.5f;
    return s;
}

__device__ __forceinline__ double wredD(double v) {
#pragma unroll
    for (int o = 32; o > 0; o >>= 1) v += __shfl_down(v, o, 64);
    return v;
}
__device__ __forceinline__ int wredI(int v) {
#pragma unroll
    for (int o = 32; o > 0; o >>= 1) v += __shfl_down(v, o, 64);
    return v;
}

// K1: full pass. BCE everywhere; loc loads ONLY for positives (~2%) so HBM
// fetches only the cache lines that contain a positive.
__global__ void __launch_bounds__(256)
mbl_k1(const float4* __restrict__ loc4, const float* __restrict__ conf,
       const float4* __restrict__ loct4, const int* __restrict__ conft,
       unsigned char* __restrict__ ws)
{
    __shared__ unsigned int lh[4096];
    __shared__ double wsum[4], wbce[4];
    __shared__ int wnp[4];
    for (int i = threadIdx.x; i < 4096; i += 256) lh[i] = 0;
    __syncthreads();

    const int row = blockIdx.x / BPR;
    const int chunk = blockIdx.x % BPR;
    const int base = row * D_ + chunk * CHUNK;

    const float4* c4 = (const float4*)(conf + base);
    const int4*   t4 = (const int4*)(conft + base);
    float4* bn4 = (float4*)(ws + OFF_BCENEG) + (base >> 2);

    double sl1 = 0.0, bcep = 0.0;
    int np = 0;

    for (int g = threadIdx.x; g < GROUPS; g += 256) {
        float4 x = c4[g];
        int4 t = t4[g];
        const int e = base + g * 4;
        float4 bn;
        {
            float b = bce_logits(x.x, t.x);
            if (t.x > 0) { np++; bcep += (double)b; bn.x = 0.0f;
                sl1 += (double)smooth_l1_4(loc4[e + 0], loct4[e + 0]); }
            else { bn.x = b; atomicAdd(&lh[__float_as_uint(b) >> 20], 1u); }
        }
        {
            float b = bce_logits(x.y, t.y);
            if (t.y > 0) { np++; bcep += (double)b; bn.y = 0.0f;
                sl1 += (double)smooth_l1_4(loc4[e + 1], loct4[e + 1]); }
            else { bn.y = b; atomicAdd(&lh[__float_as_uint(b) >> 20], 1u); }
        }
        {
            float b = bce_logits(x.z, t.z);
            if (t.z > 0) { np++; bcep += (double)b; bn.z = 0.0f;
                sl1 += (double)smooth_l1_4(loc4[e + 2], loct4[e + 2]); }
            else { bn.z = b; atomicAdd(&lh[__float_as_uint(b) >> 20], 1u); }
        }
        {
            float b = bce_logits(x.w, t.w);
            if (t.w > 0) { np++; bcep += (double)b; bn.w = 0.0f;
                sl1 += (double)smooth_l1_4(loc4[e + 3], loct4[e + 3]); }
            else { bn.w = b; atomicAdd(&lh[__float_as_uint(b) >> 20], 1u); }
        }
        bn4[g] = bn;
    }
    __syncthreads();

    unsigned int* gh = (unsigned int*)(ws + OFF_HIST) + row * 4096;
    for (int i = threadIdx.x; i < 4096; i += 256) {
        unsigned int c = lh[i];
        if (c) atomicAdd(&gh[i], c);   // conditional flush: ~100 live bins only
    }

    double s = wredD(sl1), bc = wredD(bcep);
    int n = wredI(np);
    const int lane = threadIdx.x & 63, wid = threadIdx.x >> 6;
    if (lane == 0) { wsum[wid] = s; wbce[wid] = bc; wnp[wid] = n; }
    __syncthreads();
    if (threadIdx.x == 0) {
        atomicAdd((double*)(ws + OFF_SL1),  wsum[0] + wsum[1] + wsum[2] + wsum[3]);
        atomicAdd((double*)(ws + OFF_BCEP), wbce[0] + wbce[1] + wbce[2] + wbce[3]);
        atomicAdd((int*)(ws + OFF_NUMPOS) + row, wnp[0] + wnp[1] + wnp[2] + wnp[3]);
    }
}

// K2: per-row suffix scan of the level-1 histogram -> coarse bin J1, rem1, k.
__global__ void __launch_bounds__(256)
mbl_k2(unsigned char* __restrict__ ws)
{
    __shared__ unsigned int lh[4096];
    __shared__ unsigned int csum[256];
    const int row = blockIdx.x;
    const unsigned int* gh = (const unsigned int*)(ws + OFF_HIST) + row * 4096;
    for (int i = threadIdx.x; i < 4096; i += 256) lh[i] = gh[i];
    __syncthreads();
    unsigned int s = 0;
    const int c0 = threadIdx.x * 16;
    for (int i = 0; i < 16; i++) s += lh[c0 + i];
    csum[threadIdx.x] = s;
    __syncthreads();
    if (threadIdx.x == 0) {
        const int np = ((const int*)(ws + OFF_NUMPOS))[row];
        long long k = (long long)np * NEGPOS;
        if (k > D_) k = D_;
        long long cum = 0; int J = 4096; int rem = 0; bool found = false;
        if (k > 0) {
            for (int c = 255; c >= 0; c--) {
                if (cum + (long long)csum[c] >= k) {
                    for (int b = c * 16 + 15; b >= c * 16; b--) {
                        cum += lh[b];
                        if (cum >= k) {
                            J = b; rem = (int)(k - (cum - (long long)lh[b]));
                            found = true; break;
                        }
                    }
                    break;
                }
                cum += csum[c];
            }
        }
        if (!found) { J = 4096; rem = 0; }
        ((int*)(ws + OFF_J1))[row] = J;
        ((int*)(ws + OFF_REM1))[row] = rem;
        ((int*)(ws + OFF_KK))[row] = (int)k;
    }
}

// K3: pass over bce_neg: sum values in bins > J1 (all definitely selected),
// gather bin-J1 candidates for exact refinement.
__global__ void __launch_bounds__(256)
mbl_k3(unsigned char* __restrict__ ws)
{
    const int row = blockIdx.x / BPR;
    const int chunk = blockIdx.x % BPR;
    const int base = row * D_ + chunk * CHUNK;
    const float4* in4 = (const float4*)(ws + OFF_BCENEG) + (base >> 2);
    const int j1 = ((const int*)(ws + OFF_J1))[row];
    unsigned int* ccnt = (unsigned int*)(ws + OFF_CANDCNT) + row;
    float* cand = (float*)(ws + OFF_CAND) + row * CAP;
    double acc = 0.0;

    for (int g = threadIdx.x; g < GROUPS; g += 256) {
        float4 v = in4[g];
#pragma unroll
        for (int c = 0; c < 4; c++) {
            float f = (c == 0) ? v.x : (c == 1) ? v.y : (c == 2) ? v.z : v.w;
            unsigned u = __float_as_uint(f);
            int bin = (int)(u >> 20);
            if (bin > j1) acc += (double)f;
            else if (bin == j1) {
                unsigned p = atomicAdd(ccnt, 1u);
                if (p < CAP) cand[p] = f;
            }
        }
    }
    __shared__ double wr[4];
    double t = wredD(acc);
    const int lane = threadIdx.x & 63, wid = threadIdx.x >> 6;
    if (lane == 0) wr[wid] = t;
    __syncthreads();
    if (threadIdx.x == 0)
        atomicAdd((double*)(ws + OFF_NEGSUM) + row, wr[0] + wr[1] + wr[2] + wr[3]);
}

// K4: exact refinement within bin J1: level 2 on bits 19:8, level 3 on bits
// 7:0. Final: negsum += sum(values > T) + ties_selected * T.
__global__ void __launch_bounds__(256)
mbl_k4(unsigned char* __restrict__ ws)
{
    __shared__ unsigned int h2[4096];
    __shared__ float s2[4096];
    __shared__ unsigned int h3[256];
    __shared__ float s3[256];
    __shared__ unsigned int csum[256];
    __shared__ int shJ2, shRem2;
    __shared__ double wr[4];

    const int row = blockIdx.x;
    const int r1 = ((const int*)(ws + OFF_REM1))[row];
    if (r1 <= 0) return;
    const int j1 = ((const int*)(ws + OFF_J1))[row];
    const unsigned int nc = ((const unsigned int*)(ws + OFF_CANDCNT))[row];
    const int n = (int)((nc < (unsigned)CAP) ? nc : (unsigned)CAP);
    const float* cand = (const float*)(ws + OFF_CAND) + row * CAP;

    for (int i = threadIdx.x; i < 4096; i += 256) { h2[i] = 0; s2[i] = 0.0f; }
    __syncthreads();
    for (int i = threadIdx.x; i < n; i += 256) {
        float f = cand[i];
        unsigned u = __float_as_uint(f);
        int b2 = (int)((u >> 8) & 0xFFFu);
        atomicAdd(&h2[b2], 1u);
        atomicAdd(&s2[b2], f);
    }
    __syncthreads();
    {
        unsigned s = 0; const int c0 = threadIdx.x * 16;
        for (int i = 0; i < 16; i++) s += h2[c0 + i];
        csum[threadIdx.x] = s;
    }
    __syncthreads();
    if (threadIdx.x == 0) {
        long long cum = 0; int J = -1; int rem = 0;
        for (int c = 255; c >= 0; c--) {
            if (cum + (long long)csum[c] >= (long long)r1) {
                for (int b = c * 16 + 15; b >= c * 16; b--) {
                    cum += h2[b];
                    if (cum >= r1) { J = b; rem = (int)((long long)r1 - (cum - (long long)h2[b])); break; }
                }
                break;
            }
            cum += csum[c];
        }
        shJ2 = J; shRem2 = rem;
    }
    __syncthreads();
    const int j2 = shJ2; const int r2 = shRem2;
    if (j2 < 0) return;   // pathological overflow guard (can't happen here)

    double sa2 = 0.0;
    for (int i = threadIdx.x; i < 4096; i += 256)
        if (i > j2) sa2 += (double)s2[i];

    if (threadIdx.x < 256) { h3[threadIdx.x & 255] = 0; s3[threadIdx.x & 255] = 0.0f; }
    __syncthreads();
    for (int i = threadIdx.x; i < n; i += 256) {
        float f = cand[i];
        unsigned u = __float_as_uint(f);
        if ((int)((u >> 8) & 0xFFFu) == j2) {
            atomicAdd(&h3[u & 0xFFu], 1u);
            atomicAdd(&s3[u & 0xFFu], f);
        }
    }
    __syncthreads();

    double t = wredD(sa2);
    const int lane = threadIdx.x & 63, wid = threadIdx.x >> 6;
    if (lane == 0) wr[wid] = t;
    __syncthreads();
    if (threadIdx.x == 0) {
        double SA2 = wr[0] + wr[1] + wr[2] + wr[3];
        long long cum = 0; int J3 = 0; int rem3 = 0;
        for (int b = 255; b >= 0; b--) {
            cum += h3[b];
            if (cum >= r2) { J3 = b; rem3 = (int)((long long)r2 - (cum - (long long)h3[b])); break; }
        }
        double SA3 = 0.0;
        for (int b = 255; b > J3; b--) SA3 += (double)s3[b];
        unsigned Tb = ((unsigned)j1 << 20) | ((unsigned)j2 << 8) | (unsigned)J3;
        double T = (double)__uint_as_float(Tb);
        double* ns = (double*)(ws + OFF_NEGSUM) + row;
        *ns += SA2 + SA3 + (double)rem3 * T;   // sole writer at this point
    }
}

// K5: combine -> two output scalars.
__global__ void __launch_bounds__(64)
mbl_k5(unsigned char* __restrict__ ws, float* __restrict__ out)
{
    const int t = threadIdx.x;                  // 64 threads = 64 rows
    int np = ((const int*)(ws + OFF_NUMPOS))[t];
    int k  = ((const int*)(ws + OFF_KK))[t];
    double ns = ((const double*)(ws + OFF_NEGSUM))[t];
    int npT = wredI(np);
    int kT  = wredI(k);
    double nsT = wredD(ns);
    if (t == 0) {
        double Np = (double)npT;
        double sl1  = *((const double*)(ws + OFF_SL1));
        double bcep = *((const double*)(ws + OFF_BCEP));
        double out0 = (Np > 0.0) ? (sl1 / (4.0 * Np)) / Np : 0.0;
        double denom = Np + (double)kT;
        double out1 = (Np > 0.0 && denom > 0.0) ? ((bcep + nsT) / denom) / Np : 0.0;
        out[0] = (float)out0;
        out[1] = (float)out1;
    }
}

extern "C" void kernel_launch(void* const* d_in, const int* in_sizes, int n_in,
                              void* d_out, int out_size, void* d_ws, size_t ws_size,
                              hipStream_t stream)
{
    const float4* loc4  = (const float4*)d_in[0];   // (B,D,4) f32
    const float*  conf  = (const float*)d_in[1];    // (B,D,1) f32
    const float4* loct4 = (const float4*)d_in[2];   // (B,D,4) f32
    const int*    conft = (const int*)d_in[3];      // (B,D)   i32
    unsigned char* ws = (unsigned char*)d_ws;
    float* out = (float*)d_out;

    hipMemsetAsync(ws, 0, ZERO_BYTES, stream);
    mbl_k1<<<dim3(B_ * BPR), dim3(256), 0, stream>>>(loc4, conf, loct4, conft, ws);
    mbl_k2<<<dim3(B_), dim3(256), 0, stream>>>(ws);
    mbl_k3<<<dim3(B_ * BPR), dim3(256), 0, stream>>>(ws);
    mbl_k4<<<dim3(B_), dim3(256), 0, stream>>>(ws);
    mbl_k5<<<dim3(1), dim3(64), 0, stream>>>(ws, out);
}

// Round 2
// 239.964 us; speedup vs baseline: 1.8589x; 1.8589x over previous
//
#include <hip/hip_runtime.h>
#include <stdint.h>

// MultiBoxLoss: B=64 rows, D=65536 anchors, ~2% positives.
// R2: select hard negatives by RAW LOGIT x (softplus is monotone -> same
// top-k value multiset as selecting by bce), 256 linear bins over x in
// [-2,6) for the coarse histogram (low atomic collision), LDS-staged
// candidate gather with ONE global atomic per block (R1's 209us K3 was
// per-element contended global atomics on a single counter dword).

#define B_ 64
#define D_ 65536
#define NEGPOS 3
#define BPR 16                 // blocks per row for full-pass kernels
#define CHUNK (D_ / BPR)       // 4096 elements per block
#define GROUPS (CHUNK / 4)     // 1024 float4 groups per block
#define NB 256                 // level-1 histogram bins
#define XLO 2.0f               // bin = floor((x + XLO) * XSC)
#define XSC 32.0f
#define CAP 32768              // per-row candidate capacity (expect ~250)

// ---------------- ws layout (bytes) ----------------
// zeroed region (one hipMemsetAsync):
#define OFF_SL1      0                          // double: sum smooth_l1 over pos
#define OFF_BCEP     8                          // double: sum bce over pos
#define OFF_NUMPOS   16                         // int[64]
#define OFF_CANDCNT  272                        // u32[64]
#define OFF_NEGSUM   528                        // double[64]
#define OFF_HIST     1040                       // u32[64*256]
#define ZERO_BYTES   (1040 + 64 * NB * 4)       // 66,576
// non-zeroed:
#define OFF_J1       66688                      // int[64]
#define OFF_REM1     66944                      // int[64]
#define OFF_KSEL     67200                      // int[64]
#define OFF_CAND     67520                      // float[64*CAP]

__device__ __forceinline__ float softplus_f(float x) {   // bce for t=0
    return fmaxf(x, 0.0f) + log1pf(expf(-fabsf(x)));
}

__device__ __forceinline__ int bin_of(float x) {
    int b = (int)floorf((x + XLO) * XSC);
    return max(0, min(NB - 1, b));
}

__device__ __forceinline__ unsigned sortkey(float x) {   // uint order == float order
    unsigned u = __float_as_uint(x);
    return (u & 0x80000000u) ? ~u : (u | 0x80000000u);
}
__device__ __forceinline__ float unsortkey(unsigned s) {
    unsigned u = (s & 0x80000000u) ? (s & 0x7FFFFFFFu) : ~s;
    return __uint_as_float(u);
}

__device__ __forceinline__ float smooth_l1_4(float4 a, float4 b) {
    float s = 0.0f, d, ad;
    d = a.x - b.x; ad = fabsf(d); s += (ad < 1.0f) ? 0.5f * d * d : ad - 0.5f;
    d = a.y - b.y; ad = fabsf(d); s += (ad < 1.0f) ? 0.5f * d * d : ad - 0.5f;
    d = a.z - b.z; ad = fabsf(d); s += (ad < 1.0f) ? 0.5f * d * d : ad - 0.5f;
    d = a.w - b.w; ad = fabsf(d); s += (ad < 1.0f) ? 0.5f * d * d : ad - 0.5f;
    return s;
}

__device__ __forceinline__ double wredD(double v) {
#pragma unroll
    for (int o = 32; o > 0; o >>= 1) v += __shfl_down(v, o, 64);
    return v;
}
__device__ __forceinline__ int wredI(int v) {
#pragma unroll
    for (int o = 32; o > 0; o >>= 1) v += __shfl_down(v, o, 64);
    return v;
}

// K1: full pass. Histogram x for negatives; pos sums (bce, smooth_l1) with
// loc loads ONLY for positives (~2% -> only those cache lines fetched).
__global__ void __launch_bounds__(256)
mbl_k1(const float4* __restrict__ loc4, const float* __restrict__ conf,
       const float4* __restrict__ loct4, const int* __restrict__ conft,
       unsigned char* __restrict__ ws)
{
    __shared__ unsigned int lh[NB];
    __shared__ double wsum[4], wbce[4];
    __shared__ int wnp[4];
    if (threadIdx.x < NB) lh[threadIdx.x] = 0;
    __syncthreads();

    const int row = blockIdx.x / BPR;
    const int chunk = blockIdx.x % BPR;
    const int base = row * D_ + chunk * CHUNK;

    const float4* c4 = (const float4*)(conf + base);
    const int4*   t4 = (const int4*)(conft + base);

    double sl1 = 0.0, bcep = 0.0;
    int np = 0;

    for (int g = threadIdx.x; g < GROUPS; g += 256) {
        float4 x = c4[g];
        int4 t = t4[g];
        const int e = base + g * 4;
#pragma unroll
        for (int c = 0; c < 4; c++) {
            float xv = (c == 0) ? x.x : (c == 1) ? x.y : (c == 2) ? x.z : x.w;
            int   tv = (c == 0) ? t.x : (c == 1) ? t.y : (c == 2) ? t.z : t.w;
            if (tv > 0) {
                np++;
                bcep += (double)(softplus_f(xv) - xv);   // bce with t=1
                sl1 += (double)smooth_l1_4(loc4[e + c], loct4[e + c]);
            } else {
                atomicAdd(&lh[bin_of(xv)], 1u);
            }
        }
    }
    __syncthreads();

    unsigned int* gh = (unsigned int*)(ws + OFF_HIST) + row * NB;
    if (threadIdx.x < NB) {
        unsigned int c = lh[threadIdx.x];
        if (c) atomicAdd(&gh[threadIdx.x], c);
    }

    double s = wredD(sl1), bc = wredD(bcep);
    int n = wredI(np);
    const int lane = threadIdx.x & 63, wid = threadIdx.x >> 6;
    if (lane == 0) { wsum[wid] = s; wbce[wid] = bc; wnp[wid] = n; }
    __syncthreads();
    if (threadIdx.x == 0) {
        atomicAdd((double*)(ws + OFF_SL1),  wsum[0] + wsum[1] + wsum[2] + wsum[3]);
        atomicAdd((double*)(ws + OFF_BCEP), wbce[0] + wbce[1] + wbce[2] + wbce[3]);
        atomicAdd((int*)(ws + OFF_NUMPOS) + row, wnp[0] + wnp[1] + wnp[2] + wnp[3]);
    }
}

// K2: per-row suffix scan of 256-bin histogram -> J1 (bin holding k-th), rem1, ksel.
__global__ void __launch_bounds__(256)
mbl_k2(unsigned char* __restrict__ ws)
{
    __shared__ unsigned int lh[NB];
    const int row = blockIdx.x;
    const unsigned int* gh = (const unsigned int*)(ws + OFF_HIST) + row * NB;
    if (threadIdx.x < NB) lh[threadIdx.x] = gh[threadIdx.x];
    __syncthreads();
    if (threadIdx.x == 0) {
        const int np = ((const int*)(ws + OFF_NUMPOS))[row];
        long long k = (long long)np * NEGPOS;
        if (k > D_) k = D_;
        long long negs = (long long)D_ - np;       // reference: selected negs
        if (k > negs) k = negs;                    // can't exceed #negatives
        int J = NB; int rem = 0;
        if (k > 0) {
            long long cum = 0;
            for (int b = NB - 1; b >= 0; b--) {
                cum += lh[b];
                if (cum >= k) { J = b; rem = (int)(k - (cum - (long long)lh[b])); break; }
            }
        }
        ((int*)(ws + OFF_J1))[row] = J;
        ((int*)(ws + OFF_REM1))[row] = rem;
        ((int*)(ws + OFF_KSEL))[row] = (int)k;
    }
}

// K3: pass over conf/conft: sum softplus(x) for negatives in bins > J1
// (definitely selected); gather bin-J1 candidates via LDS staging with a
// single global atomic per block.
__global__ void __launch_bounds__(256)
mbl_k3(const float* __restrict__ conf, const int* __restrict__ conft,
       unsigned char* __restrict__ ws)
{
    __shared__ float lcand[CHUNK];     // worst case: whole chunk in bin J1
    __shared__ unsigned int lcnt, gbase;
    __shared__ double wr[4];
    if (threadIdx.x == 0) lcnt = 0;
    __syncthreads();

    const int row = blockIdx.x / BPR;
    const int chunk = blockIdx.x % BPR;
    const int base = row * D_ + chunk * CHUNK;
    const float4* c4 = (const float4*)(conf + base);
    const int4*   t4 = (const int4*)(conft + base);
    const int j1 = ((const int*)(ws + OFF_J1))[row];
    double acc = 0.0;

    for (int g = threadIdx.x; g < GROUPS; g += 256) {
        float4 x = c4[g];
        int4 t = t4[g];
#pragma unroll
        for (int c = 0; c < 4; c++) {
            float xv = (c == 0) ? x.x : (c == 1) ? x.y : (c == 2) ? x.z : x.w;
            int   tv = (c == 0) ? t.x : (c == 1) ? t.y : (c == 2) ? t.z : t.w;
            if (tv <= 0) {
                int b = bin_of(xv);
                if (b > j1) acc += (double)softplus_f(xv);
                else if (b == j1) {
                    unsigned p = atomicAdd(&lcnt, 1u);   // LDS atomic, ~15/block
                    lcand[p] = xv;
                }
            }
        }
    }
    __syncthreads();
    if (threadIdx.x == 0)
        gbase = atomicAdd((unsigned int*)(ws + OFF_CANDCNT) + row, lcnt);
    __syncthreads();
    float* cand = (float*)(ws + OFF_CAND) + row * CAP;
    const unsigned n = lcnt, b0 = gbase;
    for (unsigned i = threadIdx.x; i < n; i += 256) {
        unsigned p = b0 + i;
        if (p < CAP) cand[p] = lcand[i];
    }

    double t = wredD(acc);
    const int lane = threadIdx.x & 63, wid = threadIdx.x >> 6;
    if (lane == 0) wr[wid] = t;
    __syncthreads();
    if (threadIdx.x == 0)
        atomicAdd((double*)(ws + OFF_NEGSUM) + row, wr[0] + wr[1] + wr[2] + wr[3]);
}

// K4: exact radix select (4 x 8-bit digits on sortable keys) among ~250
// candidates; add sum(selected bce) to NEGSUM. Ties: rem * softplus(x_T).
__global__ void __launch_bounds__(256)
mbl_k4(unsigned char* __restrict__ ws)
{
    __shared__ unsigned int h[256];
    __shared__ int shD, shRem;
    __shared__ double wr[4];

    const int row = blockIdx.x;
    const int rem1 = ((const int*)(ws + OFF_REM1))[row];
    if (rem1 <= 0) return;
    const unsigned int nc = ((const unsigned int*)(ws + OFF_CANDCNT))[row];
    const int n = (int)((nc < (unsigned)CAP) ? nc : (unsigned)CAP);
    const float* cand = (const float*)(ws + OFF_CAND) + row * CAP;

    unsigned pref = 0, maskHi = 0;
    int rem = rem1;
#pragma unroll
    for (int pass = 3; pass >= 0; pass--) {
        h[threadIdx.x] = 0;
        __syncthreads();
        for (int i = threadIdx.x; i < n; i += 256) {
            unsigned key = sortkey(cand[i]);
            if ((key & maskHi) == pref)
                atomicAdd(&h[(key >> (8 * pass)) & 255u], 1u);
        }
        __syncthreads();
        if (threadIdx.x == 0) {
            long long cum = 0; int d = 0, r = rem;
            for (int b = 255; b >= 0; b--) {
                cum += h[b];
                if (cum >= rem) { d = b; r = (int)((long long)rem - (cum - (long long)h[b])); break; }
            }
            shD = d; shRem = r;
        }
        __syncthreads();
        pref |= ((unsigned)shD) << (8 * pass);
        maskHi = (pass == 0) ? 0xFFFFFFFFu : (0xFFFFFFFFu << (8 * pass));
        rem = shRem;
        __syncthreads();
    }
    const unsigned Tkey = pref;
    const float xT = unsortkey(Tkey);

    double acc = 0.0;
    for (int i = threadIdx.x; i < n; i += 256) {
        float xv = cand[i];
        if (sortkey(xv) > Tkey) acc += (double)softplus_f(xv);
    }
    double t = wredD(acc);
    const int lane = threadIdx.x & 63, wid = threadIdx.x >> 6;
    if (lane == 0) wr[wid] = t;
    __syncthreads();
    if (threadIdx.x == 0) {
        double* ns = (double*)(ws + OFF_NEGSUM) + row;   // sole writer now
        *ns += wr[0] + wr[1] + wr[2] + wr[3] + (double)rem * (double)softplus_f(xT);
    }
}

// K5: combine -> two output scalars.
__global__ void __launch_bounds__(64)
mbl_k5(unsigned char* __restrict__ ws, float* __restrict__ out)
{
    const int t = threadIdx.x;                  // 64 threads = 64 rows
    int np = ((const int*)(ws + OFF_NUMPOS))[t];
    int k  = ((const int*)(ws + OFF_KSEL))[t];
    double ns = ((const double*)(ws + OFF_NEGSUM))[t];
    int npT = wredI(np);
    int kT  = wredI(k);
    double nsT = wredD(ns);
    if (t == 0) {
        double Np = (double)npT;
        double sl1  = *((const double*)(ws + OFF_SL1));
        double bcep = *((const double*)(ws + OFF_BCEP));
        double out0 = (Np > 0.0) ? (sl1 / (4.0 * Np)) / Np : 0.0;
        double denom = Np + (double)kT;
        double out1 = (Np > 0.0 && denom > 0.0) ? ((bcep + nsT) / denom) / Np : 0.0;
        out[0] = (float)out0;
        out[1] = (float)out1;
    }
}

extern "C" void kernel_launch(void* const* d_in, const int* in_sizes, int n_in,
                              void* d_out, int out_size, void* d_ws, size_t ws_size,
                              hipStream_t stream)
{
    const float4* loc4  = (const float4*)d_in[0];   // (B,D,4) f32
    const float*  conf  = (const float*)d_in[1];    // (B,D,1) f32
    const float4* loct4 = (const float4*)d_in[2];   // (B,D,4) f32
    const int*    conft = (const int*)d_in[3];      // (B,D)   i32
    unsigned char* ws = (unsigned char*)d_ws;
    float* out = (float*)d_out;

    hipMemsetAsync(ws, 0, ZERO_BYTES, stream);
    mbl_k1<<<dim3(B_ * BPR), dim3(256), 0, stream>>>(loc4, conf, loct4, conft, ws);
    mbl_k2<<<dim3(B_), dim3(256), 0, stream>>>(ws);
    mbl_k3<<<dim3(B_ * BPR), dim3(256), 0, stream>>>(conf, conft, ws);
    mbl_k4<<<dim3(B_), dim3(256), 0, stream>>>(ws);
    mbl_k5<<<dim3(1), dim3(64), 0, stream>>>(ws, out);
}

// Round 3
// 229.728 us; speedup vs baseline: 1.9417x; 1.0446x over previous
//
#include <hip/hip_runtime.h>
#include <stdint.h>

// MultiBoxLoss: B=64 rows, D=65536 anchors, ~2% positives.
// R3: single streaming pass (conf+conft only), static cutoff XC compacts
// ~10%/row candidate negatives (k-th value ~= x@top-6% >> XC whp; exact
// fallback if not). Positives -> index list, gathered by a dedicated
// massively-parallel kernel (R2's K1 was latency-bound on in-loop divergent
// gathers). Exact top-k via 4x8-bit radix select over compacted candidates.

#define B_ 64
#define D_ 65536
#define NEGPOS 3
#define BPR 16                 // blocks per row for the streaming kernel
#define CHUNK (D_ / BPR)       // 4096 elements per block
#define GROUPS (CHUNK / 4)     // 1024 float4 groups per block
#define XC 1.25f               // candidate cutoff (P(x>=XC)~10.6% per row)
#define CAPC 16384             // per-row candidate capacity (expect ~6.8k)

// ---------------- ws layout (bytes) ----------------
// zeroed region (one hipMemsetAsync):
#define OFF_SL1      0                          // double
#define OFF_BCEP     8                          // double
#define OFF_NEGSUM   16                         // double[64]
#define OFF_NUMPOS   528                        // int[64]
#define OFF_CANDCNT  784                        // u32[64]
#define OFF_POSCNT   1040                       // u32
#define ZERO_BYTES   1056
// non-zeroed:
#define OFF_KSEL     1056                       // int[64]
#define OFF_CAND     2048                       // float[64*CAPC]  (4 MiB)
#define OFF_POSL     (2048 + 64 * CAPC * 4)     // u32[B_*D_]      (16 MiB worst case)

__device__ __forceinline__ float softplus_f(float x) {   // bce for t=0
    return fmaxf(x, 0.0f) + log1pf(expf(-fabsf(x)));
}

__device__ __forceinline__ unsigned sortkey(float x) {   // uint order == float order
    unsigned u = __float_as_uint(x);
    return (u & 0x80000000u) ? ~u : (u | 0x80000000u);
}
__device__ __forceinline__ float unsortkey(unsigned s) {
    unsigned u = (s & 0x80000000u) ? (s & 0x7FFFFFFFu) : ~s;
    return __uint_as_float(u);
}

__device__ __forceinline__ float smooth_l1_4(float4 a, float4 b) {
    float s = 0.0f, d, ad;
    d = a.x - b.x; ad = fabsf(d); s += (ad < 1.0f) ? 0.5f * d * d : ad - 0.5f;
    d = a.y - b.y; ad = fabsf(d); s += (ad < 1.0f) ? 0.5f * d * d : ad - 0.5f;
    d = a.z - b.z; ad = fabsf(d); s += (ad < 1.0f) ? 0.5f * d * d : ad - 0.5f;
    d = a.w - b.w; ad = fabsf(d); s += (ad < 1.0f) ? 0.5f * d * d : ad - 0.5f;
    return s;
}

__device__ __forceinline__ double wredD(double v) {
#pragma unroll
    for (int o = 32; o > 0; o >>= 1) v += __shfl_down(v, o, 64);
    return v;
}
__device__ __forceinline__ int wredI(int v) {
#pragma unroll
    for (int o = 32; o > 0; o >>= 1) v += __shfl_down(v, o, 64);
    return v;
}

// K1: ONE coalesced pass over conf+conft. Compacts candidate negatives
// (x >= XC) and positive indices into LDS, flushes each with one global
// atomic per block. bce_pos from the streamed value (no gather).
__global__ void __launch_bounds__(256)
mbl_k1(const float* __restrict__ conf, const int* __restrict__ conft,
       unsigned char* __restrict__ ws)
{
    __shared__ float lcand[CHUNK];
    __shared__ unsigned lpos[CHUNK];
    __shared__ unsigned ccnt_s, pcnt_s, cbase_s, pbase_s;
    __shared__ double wbce[4];
    __shared__ int wnp[4];
    if (threadIdx.x == 0) { ccnt_s = 0; pcnt_s = 0; }
    __syncthreads();

    const int row = blockIdx.x / BPR;
    const int chunk = blockIdx.x % BPR;
    const int base = row * D_ + chunk * CHUNK;
    const float4* c4 = (const float4*)(conf + base);
    const int4*   t4 = (const int4*)(conft + base);

    // hoist all global loads (4 x 32B per thread) for max MLP
    float4 xv[4]; int4 tv[4];
#pragma unroll
    for (int it = 0; it < 4; it++) {
        const int g = threadIdx.x + it * 256;
        xv[it] = c4[g];
        tv[it] = t4[g];
    }

    double bcep = 0.0;
    int np = 0;
#pragma unroll
    for (int it = 0; it < 4; it++) {
        const int g = threadIdx.x + it * 256;
#pragma unroll
        for (int c = 0; c < 4; c++) {
            float x = (c == 0) ? xv[it].x : (c == 1) ? xv[it].y : (c == 2) ? xv[it].z : xv[it].w;
            int   t = (c == 0) ? tv[it].x : (c == 1) ? tv[it].y : (c == 2) ? tv[it].z : tv[it].w;
            if (t > 0) {
                np++;
                bcep += (double)(softplus_f(x) - x);     // bce with t=1
                unsigned p = atomicAdd(&pcnt_s, 1u);     // LDS, ~1 lane/wave-op
                lpos[p] = (unsigned)(base + g * 4 + c);
            } else if (x >= XC) {
                unsigned p = atomicAdd(&ccnt_s, 1u);     // LDS, ~7 lanes/wave-op
                lcand[p] = x;
            }
        }
    }
    __syncthreads();

    if (threadIdx.x == 0) {
        cbase_s = atomicAdd((unsigned*)(ws + OFF_CANDCNT) + row, ccnt_s);
        pbase_s = atomicAdd((unsigned*)(ws + OFF_POSCNT), pcnt_s);
    }
    __syncthreads();
    {
        float* cand = (float*)(ws + OFF_CAND) + row * CAPC;
        const unsigned n = ccnt_s, b0 = cbase_s;
        for (unsigned i = threadIdx.x; i < n; i += 256) {
            unsigned p = b0 + i;
            if (p < CAPC) cand[p] = lcand[i];            // overflow -> Ksel fallback
        }
        unsigned* posl = (unsigned*)(ws + OFF_POSL);
        const unsigned m = pcnt_s, p0 = pbase_s;
        for (unsigned i = threadIdx.x; i < m; i += 256)
            posl[p0 + i] = lpos[i];                      // capacity B*D: can't overflow
    }

    double bc = wredD(bcep);
    int n = wredI(np);
    const int lane = threadIdx.x & 63, wid = threadIdx.x >> 6;
    if (lane == 0) { wbce[wid] = bc; wnp[wid] = n; }
    __syncthreads();
    if (threadIdx.x == 0) {
        atomicAdd((double*)(ws + OFF_BCEP), wbce[0] + wbce[1] + wbce[2] + wbce[3]);
        atomicAdd((int*)(ws + OFF_NUMPOS) + row, wnp[0] + wnp[1] + wnp[2] + wnp[3]);
    }
}

// Kpos: gather loc/loc_t at positive indices (flat list). One element per
// thread -> huge memory-level parallelism, zero divergence stalls.
__global__ void __launch_bounds__(256)
mbl_kpos(const float4* __restrict__ loc4, const float4* __restrict__ loct4,
         unsigned char* __restrict__ ws)
{
    __shared__ double wr[4];
    const unsigned cnt = *(const unsigned*)(ws + OFF_POSCNT);
    const unsigned* posl = (const unsigned*)(ws + OFF_POSL);
    double sl1 = 0.0;
    for (unsigned i = blockIdx.x * 256 + threadIdx.x; i < cnt; i += gridDim.x * 256) {
        unsigned e = posl[i];
        sl1 += (double)smooth_l1_4(loc4[e], loct4[e]);
    }
    double t = wredD(sl1);
    const int lane = threadIdx.x & 63, wid = threadIdx.x >> 6;
    if (lane == 0) wr[wid] = t;
    __syncthreads();
    if (threadIdx.x == 0)
        atomicAdd((double*)(ws + OFF_SL1), wr[0] + wr[1] + wr[2] + wr[3]);
}

// Ksel: one block per row. Exact top-k radix select (4 x 8-bit on sortable
// keys) over compacted candidates; NEGSUM[row] = sum softplus(selected).
// Fallback (k > n or candidate overflow): identical select over the full
// row streamed from global (L3-resident) — exact for any input.
__global__ void __launch_bounds__(256)
mbl_ksel(const float* __restrict__ conf, const int* __restrict__ conft,
         unsigned char* __restrict__ ws)
{
    __shared__ unsigned int h[256];
    __shared__ int shD, shRem;
    __shared__ double wr[4];

    const int row = blockIdx.x;
    const int np = ((const int*)(ws + OFF_NUMPOS))[row];
    long long k = (long long)np * NEGPOS;
    if (k > D_) k = D_;
    long long negs = (long long)D_ - np;
    if (k > negs) k = negs;
    if (threadIdx.x == 0) ((int*)(ws + OFF_KSEL))[row] = (int)k;
    if (k <= 0) return;                       // NEGSUM already zeroed

    const unsigned nc = ((const unsigned*)(ws + OFF_CANDCNT))[row];
    const bool fb = (nc > (unsigned)CAPC) || ((long long)nc < k);
    const float* cand = (const float*)(ws + OFF_CAND) + row * CAPC;
    const float* rowc = conf + row * D_;
    const int*   rowt = conft + row * D_;
    const int n = fb ? D_ : (int)nc;

    unsigned pref = 0, mask = 0;
    int rem = (int)k;
#pragma unroll
    for (int pass = 3; pass >= 0; pass--) {
        h[threadIdx.x] = 0;
        __syncthreads();
        for (int i = threadIdx.x; i < n; i += 256) {
            float x; bool valid;
            if (fb) { x = rowc[i]; valid = (rowt[i] <= 0); }
            else    { x = cand[i]; valid = true; }
            if (valid) {
                unsigned key = sortkey(x);
                if ((key & mask) == pref)
                    atomicAdd(&h[(key >> (8 * pass)) & 255u], 1u);
            }
        }
        __syncthreads();
        if (threadIdx.x == 0) {
            long long cum = 0; int d = 0, r = rem;
            for (int b = 255; b >= 0; b--) {
                cum += h[b];
                if (cum >= rem) { d = b; r = (int)((long long)rem - (cum - (long long)h[b])); break; }
            }
            shD = d; shRem = r;
        }
        __syncthreads();
        pref |= ((unsigned)shD) << (8 * pass);
        mask |= 0xFFu << (8 * pass);
        rem = shRem;
        __syncthreads();
    }
    const unsigned Tkey = pref;
    const float xT = unsortkey(Tkey);

    double acc = 0.0;
    for (int i = threadIdx.x; i < n; i += 256) {
        float x; bool valid;
        if (fb) { x = rowc[i]; valid = (rowt[i] <= 0); }
        else    { x = cand[i]; valid = true; }
        if (valid && sortkey(x) > Tkey) acc += (double)softplus_f(x);
    }
    double t = wredD(acc);
    const int lane = threadIdx.x & 63, wid = threadIdx.x >> 6;
    if (lane == 0) wr[wid] = t;
    __syncthreads();
    if (threadIdx.x == 0) {
        ((double*)(ws + OFF_NEGSUM))[row] =
            wr[0] + wr[1] + wr[2] + wr[3] + (double)rem * (double)softplus_f(xT);
    }
}

// K5: combine -> two output scalars.
__global__ void __launch_bounds__(64)
mbl_k5(unsigned char* __restrict__ ws, float* __restrict__ out)
{
    const int t = threadIdx.x;                  // 64 threads = 64 rows
    int np = ((const int*)(ws + OFF_NUMPOS))[t];
    int k  = ((const int*)(ws + OFF_KSEL))[t];
    double ns = ((const double*)(ws + OFF_NEGSUM))[t];
    int npT = wredI(np);
    int kT  = wredI(k);
    double nsT = wredD(ns);
    if (t == 0) {
        double Np = (double)npT;
        double sl1  = *((const double*)(ws + OFF_SL1));
        double bcep = *((const double*)(ws + OFF_BCEP));
        double out0 = (Np > 0.0) ? (sl1 / (4.0 * Np)) / Np : 0.0;
        double denom = Np + (double)kT;
        double out1 = (Np > 0.0 && denom > 0.0) ? ((bcep + nsT) / denom) / Np : 0.0;
        out[0] = (float)out0;
        out[1] = (float)out1;
    }
}

extern "C" void kernel_launch(void* const* d_in, const int* in_sizes, int n_in,
                              void* d_out, int out_size, void* d_ws, size_t ws_size,
                              hipStream_t stream)
{
    const float4* loc4  = (const float4*)d_in[0];   // (B,D,4) f32
    const float*  conf  = (const float*)d_in[1];    // (B,D,1) f32
    const float4* loct4 = (const float4*)d_in[2];   // (B,D,4) f32
    const int*    conft = (const int*)d_in[3];      // (B,D)   i32
    unsigned char* ws = (unsigned char*)d_ws;
    float* out = (float*)d_out;

    hipMemsetAsync(ws, 0, ZERO_BYTES, stream);
    mbl_k1<<<dim3(B_ * BPR), dim3(256), 0, stream>>>(conf, conft, ws);
    mbl_kpos<<<dim3(512), dim3(256), 0, stream>>>(loc4, loct4, ws);
    mbl_ksel<<<dim3(B_), dim3(256), 0, stream>>>(conf, conft, ws);
    mbl_k5<<<dim3(1), dim3(64), 0, stream>>>(ws, out);
}

// Round 4
// 206.082 us; speedup vs baseline: 2.1645x; 1.1147x over previous
//
#include <hip/hip_runtime.h>
#include <stdint.h>

// MultiBoxLoss: B=64 rows, D=65536 anchors, ~2% positives.
// R4: kill all same-address atomic serialization.
//  - k1: wave-ballot compaction (1 LDS atomic per wave-step, not per lane).
//  - ksel: 32-step binary search on sortable uint keys, candidates held in
//    VGPRs (R3's radix pass histogrammed exponent bits: ~2 live bins ->
//    ~6800 serialized same-address LDS atomics -> 63us; binary search has
//    ZERO atomics). Exact: smallest T with count(key>T) < k is the k-th
//    largest key; ties via rem * softplus(x_T).

#define B_ 64
#define D_ 65536
#define NEGPOS 3
#define BPR 16                 // blocks per row for the streaming kernel
#define CHUNK (D_ / BPR)       // 4096 elements per block
#define XC 1.25f               // candidate cutoff (P(x>=XC)~10.6% per row)
#define CAPC 16384             // per-row candidate capacity (expect ~6.8k)
#define NREG 32                // register-resident keys/thread (covers n<=8192)

// ---------------- ws layout (bytes) ----------------
// zeroed region (one hipMemsetAsync):
#define OFF_SL1      0                          // double
#define OFF_BCEP     8                          // double
#define OFF_NEGSUM   16                         // double[64]
#define OFF_NUMPOS   528                        // int[64]
#define OFF_CANDCNT  784                        // u32[64]
#define OFF_POSCNT   1040                       // u32
#define ZERO_BYTES   1056
// non-zeroed:
#define OFF_KSEL     1056                       // int[64]
#define OFF_CAND     2048                       // float[64*CAPC]  (4 MiB)
#define OFF_POSL     (2048 + 64 * CAPC * 4)     // u32[B_*D_]

__device__ __forceinline__ float softplus_f(float x) {   // bce for t=0
    return fmaxf(x, 0.0f) + log1pf(expf(-fabsf(x)));
}

__device__ __forceinline__ unsigned sortkey(float x) {   // uint order == float order
    unsigned u = __float_as_uint(x);
    return (u & 0x80000000u) ? ~u : (u | 0x80000000u);
}
__device__ __forceinline__ float unsortkey(unsigned s) {
    unsigned u = (s & 0x80000000u) ? (s & 0x7FFFFFFFu) : ~s;
    return __uint_as_float(u);
}

__device__ __forceinline__ float smooth_l1_4(float4 a, float4 b) {
    float s = 0.0f, d, ad;
    d = a.x - b.x; ad = fabsf(d); s += (ad < 1.0f) ? 0.5f * d * d : ad - 0.5f;
    d = a.y - b.y; ad = fabsf(d); s += (ad < 1.0f) ? 0.5f * d * d : ad - 0.5f;
    d = a.z - b.z; ad = fabsf(d); s += (ad < 1.0f) ? 0.5f * d * d : ad - 0.5f;
    d = a.w - b.w; ad = fabsf(d); s += (ad < 1.0f) ? 0.5f * d * d : ad - 0.5f;
    return s;
}

__device__ __forceinline__ double wredD(double v) {
#pragma unroll
    for (int o = 32; o > 0; o >>= 1) v += __shfl_down(v, o, 64);
    return v;
}
__device__ __forceinline__ int wredI(int v) {
#pragma unroll
    for (int o = 32; o > 0; o >>= 1) v += __shfl_down(v, o, 64);
    return v;
}

// Wave-aggregated compaction push: pred-lanes append val to buf (counter in
// LDS). ONE atomic per wave per call, executed by the lowest active lane.
__device__ __forceinline__ void wave_push_f(bool pred, float val,
                                            unsigned* cnt, float* buf) {
    unsigned long long m = __ballot(pred);
    if (m == 0ull) return;
    const int lane = threadIdx.x & 63;
    const int leader = (int)(__ffsll((long long)m) - 1);
    unsigned base = 0;
    if (lane == leader) base = atomicAdd(cnt, (unsigned)__popcll(m));
    base = __shfl(base, leader, 64);
    if (pred) buf[base + __popcll(m & ((1ull << lane) - 1ull))] = val;
}
__device__ __forceinline__ void wave_push_u(bool pred, unsigned val,
                                            unsigned* cnt, unsigned* buf) {
    unsigned long long m = __ballot(pred);
    if (m == 0ull) return;
    const int lane = threadIdx.x & 63;
    const int leader = (int)(__ffsll((long long)m) - 1);
    unsigned base = 0;
    if (lane == leader) base = atomicAdd(cnt, (unsigned)__popcll(m));
    base = __shfl(base, leader, 64);
    if (pred) buf[base + __popcll(m & ((1ull << lane) - 1ull))] = val;
}

// K1: ONE coalesced pass over conf+conft. Ballot-compacts candidate
// negatives (x >= XC) and positive indices; one global atomic per block.
__global__ void __launch_bounds__(256)
mbl_k1(const float* __restrict__ conf, const int* __restrict__ conft,
       unsigned char* __restrict__ ws)
{
    __shared__ float lcand[CHUNK];
    __shared__ unsigned lpos[CHUNK];
    __shared__ unsigned ccnt_s, pcnt_s, cbase_s, pbase_s;
    __shared__ double wbce[4];
    __shared__ int wnp[4];
    if (threadIdx.x == 0) { ccnt_s = 0; pcnt_s = 0; }
    __syncthreads();

    const int row = blockIdx.x / BPR;
    const int chunk = blockIdx.x % BPR;
    const int base = row * D_ + chunk * CHUNK;
    const float4* c4 = (const float4*)(conf + base);
    const int4*   t4 = (const int4*)(conft + base);

    float4 xv[4]; int4 tv[4];
#pragma unroll
    for (int it = 0; it < 4; it++) {
        const int g = threadIdx.x + it * 256;
        xv[it] = c4[g];
        tv[it] = t4[g];
    }

    double bcep = 0.0;
    int np = 0;
#pragma unroll
    for (int it = 0; it < 4; it++) {
        const int g = threadIdx.x + it * 256;
#pragma unroll
        for (int c = 0; c < 4; c++) {
            float x = (c == 0) ? xv[it].x : (c == 1) ? xv[it].y : (c == 2) ? xv[it].z : xv[it].w;
            int   t = (c == 0) ? tv[it].x : (c == 1) ? tv[it].y : (c == 2) ? tv[it].z : tv[it].w;
            const bool isp = (t > 0);
            if (isp) { np++; bcep += (double)(softplus_f(x) - x); }
            wave_push_u(isp, (unsigned)(base + g * 4 + c), &pcnt_s, lpos);
            wave_push_f(!isp && (x >= XC), x, &ccnt_s, lcand);
        }
    }
    __syncthreads();

    if (threadIdx.x == 0) {
        cbase_s = atomicAdd((unsigned*)(ws + OFF_CANDCNT) + row, ccnt_s);
        pbase_s = atomicAdd((unsigned*)(ws + OFF_POSCNT), pcnt_s);
    }
    __syncthreads();
    {
        float* cand = (float*)(ws + OFF_CAND) + row * CAPC;
        const unsigned n = ccnt_s, b0 = cbase_s;
        for (unsigned i = threadIdx.x; i < n; i += 256) {
            unsigned p = b0 + i;
            if (p < CAPC) cand[p] = lcand[i];            // overflow -> ksel fallback
        }
        unsigned* posl = (unsigned*)(ws + OFF_POSL);
        const unsigned m = pcnt_s, p0 = pbase_s;
        for (unsigned i = threadIdx.x; i < m; i += 256)
            posl[p0 + i] = lpos[i];
    }

    double bc = wredD(bcep);
    int n = wredI(np);
    const int lane = threadIdx.x & 63, wid = threadIdx.x >> 6;
    if (lane == 0) { wbce[wid] = bc; wnp[wid] = n; }
    __syncthreads();
    if (threadIdx.x == 0) {
        atomicAdd((double*)(ws + OFF_BCEP), wbce[0] + wbce[1] + wbce[2] + wbce[3]);
        atomicAdd((int*)(ws + OFF_NUMPOS) + row, wnp[0] + wnp[1] + wnp[2] + wnp[3]);
    }
}

// Kpos: gather loc/loc_t at positive indices. One element per thread.
__global__ void __launch_bounds__(256)
mbl_kpos(const float4* __restrict__ loc4, const float4* __restrict__ loct4,
         unsigned char* __restrict__ ws)
{
    __shared__ double wr[4];
    const unsigned cnt = *(const unsigned*)(ws + OFF_POSCNT);
    const unsigned* posl = (const unsigned*)(ws + OFF_POSL);
    double sl1 = 0.0;
    for (unsigned i = blockIdx.x * 256 + threadIdx.x; i < cnt; i += gridDim.x * 256) {
        unsigned e = posl[i];
        sl1 += (double)smooth_l1_4(loc4[e], loct4[e]);
    }
    double t = wredD(sl1);
    const int lane = threadIdx.x & 63, wid = threadIdx.x >> 6;
    if (lane == 0) wr[wid] = t;
    __syncthreads();
    if (threadIdx.x == 0)
        atomicAdd((double*)(ws + OFF_SL1), wr[0] + wr[1] + wr[2] + wr[3]);
}

// block-wide int sum, result returned to all threads (two syncs).
__device__ __forceinline__ int blockSumI(int v, int* sh) {
    int w = wredI(v);
    const int lane = threadIdx.x & 63, wid = threadIdx.x >> 6;
    __syncthreads();
    if (lane == 0) sh[wid] = w;
    __syncthreads();
    return sh[0] + sh[1] + sh[2] + sh[3];
}

// Ksel: one block per row. Exact k-th-largest via 32-step binary search on
// sortable keys; candidates register-resident. NEGSUM[row] = top-k sum.
__global__ void __launch_bounds__(256)
mbl_ksel(const float* __restrict__ conf, const int* __restrict__ conft,
         unsigned char* __restrict__ ws)
{
    __shared__ int shI[4];
    __shared__ double wr[4];

    const int row = blockIdx.x;
    const int np = ((const int*)(ws + OFF_NUMPOS))[row];
    long long k = (long long)np * NEGPOS;
    if (k > D_) k = D_;
    long long negs = (long long)D_ - np;
    if (k > negs) k = negs;
    if (threadIdx.x == 0) ((int*)(ws + OFF_KSEL))[row] = (int)k;
    if (k <= 0) return;

    const unsigned nc = ((const unsigned*)(ws + OFF_CANDCNT))[row];
    const bool fb = (nc > (unsigned)(NREG * 256)) || (nc > (unsigned)CAPC) ||
                    ((long long)nc < k);
    const float* cand = (const float*)(ws + OFF_CAND) + row * CAPC;
    const float* rowc = conf + row * D_;
    const int*   rowt = conft + row * D_;

    unsigned lo = 0u, hi = 0xFFFFFFFFu;   // f(lo)>=k, f(hi)=0<k (key 0 impossible)
    int rem;
    unsigned Tkey;

    if (!fb) {
        const int n = (int)nc;
        unsigned keys[NREG];
#pragma unroll
        for (int j = 0; j < NREG; j++) {
            const int i = j * 256 + (int)threadIdx.x;
            keys[j] = (i < n) ? sortkey(cand[i]) : 0u;   // sentinel 0: never > mid
        }
        for (int it = 0; it < 32; it++) {
            const unsigned mid = lo + ((hi - lo) >> 1);
            int c = 0;
#pragma unroll
            for (int j = 0; j < NREG; j++) c += (keys[j] > mid) ? 1 : 0;
            const int tot = blockSumI(c, shI);
            if ((long long)tot >= k) lo = mid; else hi = mid;
        }
        Tkey = hi;
        int c = 0;
#pragma unroll
        for (int j = 0; j < NREG; j++) c += (keys[j] > Tkey) ? 1 : 0;
        rem = (int)(k - (long long)blockSumI(c, shI));

        double acc = 0.0;
#pragma unroll
        for (int j = 0; j < NREG; j++)
            if (keys[j] > Tkey) acc += (double)softplus_f(unsortkey(keys[j]));
        double t = wredD(acc);
        const int lane = threadIdx.x & 63, wid = threadIdx.x >> 6;
        if (lane == 0) wr[wid] = t;
        __syncthreads();
        if (threadIdx.x == 0)
            ((double*)(ws + OFF_NEGSUM))[row] =
                wr[0] + wr[1] + wr[2] + wr[3] +
                (double)rem * (double)softplus_f(unsortkey(Tkey));
    } else {
        // Exactness fallback for pathological inputs: stream full row.
        for (int it = 0; it < 32; it++) {
            const unsigned mid = lo + ((hi - lo) >> 1);
            int c = 0;
            for (int i = threadIdx.x; i < D_; i += 256)
                if (rowt[i] <= 0 && sortkey(rowc[i]) > mid) c++;
            const int tot = blockSumI(c, shI);
            if ((long long)tot >= k) lo = mid; else hi = mid;
        }
        Tkey = hi;
        int c = 0;
        double acc = 0.0;
        for (int i = threadIdx.x; i < D_; i += 256) {
            if (rowt[i] <= 0) {
                float x = rowc[i];
                if (sortkey(x) > Tkey) { c++; acc += (double)softplus_f(x); }
            }
        }
        rem = (int)(k - (long long)blockSumI(c, shI));
        double t = wredD(acc);
        const int lane = threadIdx.x & 63, wid = threadIdx.x >> 6;
        if (lane == 0) wr[wid] = t;
        __syncthreads();
        if (threadIdx.x == 0)
            ((double*)(ws + OFF_NEGSUM))[row] =
                wr[0] + wr[1] + wr[2] + wr[3] +
                (double)rem * (double)softplus_f(unsortkey(Tkey));
    }
}

// K5: combine -> two output scalars.
__global__ void __launch_bounds__(64)
mbl_k5(unsigned char* __restrict__ ws, float* __restrict__ out)
{
    const int t = threadIdx.x;                  // 64 threads = 64 rows
    int np = ((const int*)(ws + OFF_NUMPOS))[t];
    int k  = ((const int*)(ws + OFF_KSEL))[t];
    double ns = ((const double*)(ws + OFF_NEGSUM))[t];
    int npT = wredI(np);
    int kT  = wredI(k);
    double nsT = wredD(ns);
    if (t == 0) {
        double Np = (double)npT;
        double sl1  = *((const double*)(ws + OFF_SL1));
        double bcep = *((const double*)(ws + OFF_BCEP));
        double out0 = (Np > 0.0) ? (sl1 / (4.0 * Np)) / Np : 0.0;
        double denom = Np + (double)kT;
        double out1 = (Np > 0.0 && denom > 0.0) ? ((bcep + nsT) / denom) / Np : 0.0;
        out[0] = (float)out0;
        out[1] = (float)out1;
    }
}

extern "C" void kernel_launch(void* const* d_in, const int* in_sizes, int n_in,
                              void* d_out, int out_size, void* d_ws, size_t ws_size,
                              hipStream_t stream)
{
    const float4* loc4  = (const float4*)d_in[0];   // (B,D,4) f32
    const float*  conf  = (const float*)d_in[1];    // (B,D,1) f32
    const float4* loct4 = (const float4*)d_in[2];   // (B,D,4) f32
    const int*    conft = (const int*)d_in[3];      // (B,D)   i32
    unsigned char* ws = (unsigned char*)d_ws;
    float* out = (float*)d_out;

    hipMemsetAsync(ws, 0, ZERO_BYTES, stream);
    mbl_k1<<<dim3(B_ * BPR), dim3(256), 0, stream>>>(conf, conft, ws);
    mbl_kpos<<<dim3(512), dim3(256), 0, stream>>>(loc4, loct4, ws);
    mbl_ksel<<<dim3(B_), dim3(256), 0, stream>>>(conf, conft, ws);
    mbl_k5<<<dim3(1), dim3(64), 0, stream>>>(ws, out);
}

// Round 5
// 195.380 us; speedup vs baseline: 2.2831x; 1.0548x over previous
//
#include <hip/hip_runtime.h>
#include <stdint.h>

// MultiBoxLoss: B=64 rows, D=65536 anchors, ~2% positives.
// R5: 3 launches, zero global atomics, zero memset.
//  - k1: per-block private output segments (no pre-zeroed counters), packed
//    prefix-scan compaction (1 scan per block instead of 32 ballots/thread),
//    in-block positive gather (kpos merged away).
//  - ksel: exact k-th largest via 32-step binary search on sortable uint
//    keys, register-resident, reading per-block segments via offset table.
//  - k5: reduce per-block partials -> 2 scalars.
// Top-5 dispatches are now the harness's 268MB d_ws re-poison (40us each);
// this round removes our remaining launch/serialization overhead.

#define B_ 64
#define D_ 65536
#define NEGPOS 3
#define BPR 16                 // blocks per row
#define NBLK (B_ * BPR)        // 1024
#define CHUNK (D_ / BPR)       // 4096 elements per block
#define XC 1.25f               // candidate cutoff (P(x>=XC)~10.6% per row)
#define CAPC 16384             // per-row candidate cap for non-fallback path
#define NREG 32                // register keys/thread (covers n<=8192)

// ---------------- ws layout (bytes), nothing needs zeroing ----------------
#define OFF_SL1P     0                      // double[NBLK]
#define OFF_BCEP     8192                   // double[NBLK]
#define OFF_NP       16384                  // u32[NBLK]
#define OFF_CC       20480                  // u32[NBLK]
#define OFF_NEGSUM   24576                  // double[64]
#define OFF_KSEL     25088                  // int[64]
#define OFF_CAND     32768                  // float[NBLK][CHUNK] = 16 MiB

__device__ __forceinline__ float softplus_f(float x) {   // bce for t=0
    return fmaxf(x, 0.0f) + log1pf(expf(-fabsf(x)));
}

__device__ __forceinline__ unsigned sortkey(float x) {   // uint order == float order
    unsigned u = __float_as_uint(x);
    return (u & 0x80000000u) ? ~u : (u | 0x80000000u);
}
__device__ __forceinline__ float unsortkey(unsigned s) {
    unsigned u = (s & 0x80000000u) ? (s & 0x7FFFFFFFu) : ~s;
    return __uint_as_float(u);
}

__device__ __forceinline__ float smooth_l1_4(float4 a, float4 b) {
    float s = 0.0f, d, ad;
    d = a.x - b.x; ad = fabsf(d); s += (ad < 1.0f) ? 0.5f * d * d : ad - 0.5f;
    d = a.y - b.y; ad = fabsf(d); s += (ad < 1.0f) ? 0.5f * d * d : ad - 0.5f;
    d = a.z - b.z; ad = fabsf(d); s += (ad < 1.0f) ? 0.5f * d * d : ad - 0.5f;
    d = a.w - b.w; ad = fabsf(d); s += (ad < 1.0f) ? 0.5f * d * d : ad - 0.5f;
    return s;
}

__device__ __forceinline__ double wredD(double v) {
#pragma unroll
    for (int o = 32; o > 0; o >>= 1) v += __shfl_down(v, o, 64);
    return v;
}
__device__ __forceinline__ int wredI(int v) {
#pragma unroll
    for (int o = 32; o > 0; o >>= 1) v += __shfl_down(v, o, 64);
    return v;
}

// K1: one coalesced pass over conf+conft per 4096-elem chunk.
// Compaction: per-thread counts packed (cand<<16 | pos), one block scan,
// predicated LDS writes, coalesced flush to this block's private segment.
// Then gather loc/loc_t for this chunk's positives (batched, independent).
__global__ void __launch_bounds__(256)
mbl_k1(const float4* __restrict__ loc4, const float* __restrict__ conf,
       const float4* __restrict__ loct4, const int* __restrict__ conft,
       unsigned char* __restrict__ ws)
{
    __shared__ float lcand[CHUNK];       // 16 KB
    __shared__ unsigned short lpos[CHUNK]; // 8 KB (local elem idx 0..4095)
    __shared__ unsigned wtot[4];
    __shared__ double wr[8];

    const int block = blockIdx.x;
    const int base = block * CHUNK;
    const float4* c4 = (const float4*)(conf + base);
    const int4*   t4 = (const int4*)(conft + base);
    const int lane = threadIdx.x & 63, wid = threadIdx.x >> 6;

    // hoisted loads: 4 x (16B + 16B) per thread
    float4 xv[4]; int4 tv[4];
#pragma unroll
    for (int it = 0; it < 4; it++) {
        const int g = threadIdx.x + it * 256;
        xv[it] = c4[g];
        tv[it] = t4[g];
    }

    // pass 1: classify + count (+ bce for positives)
    double bcep = 0.0;
    unsigned cntc = 0, cntp = 0;
#pragma unroll
    for (int it = 0; it < 4; it++) {
#pragma unroll
        for (int c = 0; c < 4; c++) {
            float x = (c == 0) ? xv[it].x : (c == 1) ? xv[it].y : (c == 2) ? xv[it].z : xv[it].w;
            int   t = (c == 0) ? tv[it].x : (c == 1) ? tv[it].y : (c == 2) ? tv[it].z : tv[it].w;
            if (t > 0) { cntp++; bcep += (double)(softplus_f(x) - x); }
            else if (x >= XC) cntc++;
        }
    }

    // packed block exclusive scan (each field <= 4096 -> no carry)
    unsigned pk = (cntc << 16) | cntp;
    unsigned incl = pk;
#pragma unroll
    for (int o = 1; o < 64; o <<= 1) {
        unsigned v = __shfl_up(incl, o, 64);
        if (lane >= o) incl += v;
    }
    unsigned excl = incl - pk;
    if (lane == 63) wtot[wid] = incl;
    __syncthreads();
    unsigned wbase = 0;
    for (int w = 0; w < wid; w++) wbase += wtot[w];
    const unsigned tot = wtot[0] + wtot[1] + wtot[2] + wtot[3];
    const unsigned totc = tot >> 16, totp = tot & 0xFFFFu;
    unsigned offc = (excl >> 16) + (wbase >> 16);
    unsigned offp = (excl & 0xFFFFu) + (wbase & 0xFFFFu);

    // pass 2: predicated LDS writes at scanned offsets
#pragma unroll
    for (int it = 0; it < 4; it++) {
#pragma unroll
        for (int c = 0; c < 4; c++) {
            float x = (c == 0) ? xv[it].x : (c == 1) ? xv[it].y : (c == 2) ? xv[it].z : xv[it].w;
            int   t = (c == 0) ? tv[it].x : (c == 1) ? tv[it].y : (c == 2) ? tv[it].z : tv[it].w;
            const int li = (threadIdx.x + it * 256) * 4 + c;
            if (t > 0) lpos[offp++] = (unsigned short)li;
            else if (x >= XC) lcand[offc++] = x;
        }
    }
    __syncthreads();

    // coalesced flush of candidates to this block's private segment
    float* seg = (float*)(ws + OFF_CAND) + (size_t)block * CHUNK;
    for (unsigned i = threadIdx.x; i < totc; i += 256) seg[i] = lcand[i];

    // batched positive gather: ~20 independent threads, one latency hit
    double sl1 = 0.0;
    for (unsigned i = threadIdx.x; i < totp; i += 256) {
        const int e = base + (int)lpos[i];
        sl1 += (double)smooth_l1_4(loc4[e], loct4[e]);
    }

    // block reductions -> per-block partials (no atomics)
    double s1 = wredD(sl1), s2 = wredD(bcep);
    if (lane == 0) { wr[wid] = s1; wr[4 + wid] = s2; }
    __syncthreads();
    if (threadIdx.x == 0) {
        ((double*)(ws + OFF_SL1P))[block] = wr[0] + wr[1] + wr[2] + wr[3];
        ((double*)(ws + OFF_BCEP))[block] = wr[4] + wr[5] + wr[6] + wr[7];
        ((unsigned*)(ws + OFF_NP))[block] = totp;
        ((unsigned*)(ws + OFF_CC))[block] = totc;
    }
}

// block-wide int sum, result valid in all threads
__device__ __forceinline__ int blockSumI(int v, int* sh) {
    int w = wredI(v);
    const int lane = threadIdx.x & 63, wid = threadIdx.x >> 6;
    __syncthreads();
    if (lane == 0) sh[wid] = w;
    __syncthreads();
    return sh[0] + sh[1] + sh[2] + sh[3];
}

// Ksel: one block per row; exact top-k sum via binary search on sortable keys.
__global__ void __launch_bounds__(256)
mbl_ksel(const float* __restrict__ conf, const int* __restrict__ conft,
         unsigned char* __restrict__ ws)
{
    __shared__ unsigned segoff[BPR + 1];
    __shared__ int shI[4];
    __shared__ double wr[4];

    const int row = blockIdx.x;
    const unsigned* cc = (const unsigned*)(ws + OFF_CC) + row * BPR;
    const unsigned* npb = (const unsigned*)(ws + OFF_NP) + row * BPR;

    if (threadIdx.x == 0) {
        unsigned o = 0;
        int np = 0;
#pragma unroll
        for (int s = 0; s < BPR; s++) { segoff[s] = o; o += cc[s]; np += (int)npb[s]; }
        segoff[BPR] = o;
        shI[0] = np;
    }
    __syncthreads();
    const int np = shI[0];
    const unsigned n = segoff[BPR];
    long long k = (long long)np * NEGPOS;
    if (k > D_) k = D_;
    long long negs = (long long)D_ - np;
    if (k > negs) k = negs;
    if (threadIdx.x == 0) ((int*)(ws + OFF_KSEL))[row] = (int)k;
    if (k <= 0) {
        if (threadIdx.x == 0) ((double*)(ws + OFF_NEGSUM))[row] = 0.0;
        return;
    }
    __syncthreads();

    const bool fb = ((long long)n < k) || (n > (unsigned)(NREG * 256)) ||
                    (n > (unsigned)CAPC);
    const float* cand = (const float*)(ws + OFF_CAND);
    const float* rowc = conf + row * D_;
    const int*   rowt = conft + row * D_;
    const int lane = threadIdx.x & 63, wid = threadIdx.x >> 6;
    unsigned lo = 0u, hi = 0xFFFFFFFFu;
    int rem;
    unsigned Tkey;

    if (!fb) {
        unsigned keys[NREG];
#pragma unroll
        for (int j = 0; j < NREG; j++) {
            const unsigned g = (unsigned)(j * 256) + threadIdx.x;
            unsigned key = 0u;                         // sentinel: never > mid
            if (g < n) {
                // find segment: binary search over 17 offsets
                int s = 0;
#pragma unroll
                for (int st = 8; st > 0; st >>= 1)
                    if (s + st <= BPR && segoff[s + st] <= g) s += st;
                const unsigned idx = g - segoff[s];
                key = sortkey(cand[(size_t)(row * BPR + s) * CHUNK + idx]);
            }
            keys[j] = key;
        }
        for (int it = 0; it < 32; it++) {
            const unsigned mid = lo + ((hi - lo) >> 1);
            int c = 0;
#pragma unroll
            for (int j = 0; j < NREG; j++) c += (keys[j] > mid) ? 1 : 0;
            const int tot = blockSumI(c, shI);
            if ((long long)tot >= k) lo = mid; else hi = mid;
        }
        Tkey = hi;
        int c = 0;
#pragma unroll
        for (int j = 0; j < NREG; j++) c += (keys[j] > Tkey) ? 1 : 0;
        rem = (int)(k - (long long)blockSumI(c, shI));

        double acc = 0.0;
#pragma unroll
        for (int j = 0; j < NREG; j++)
            if (keys[j] > Tkey) acc += (double)softplus_f(unsortkey(keys[j]));
        double t = wredD(acc);
        if (lane == 0) wr[wid] = t;
        __syncthreads();
        if (threadIdx.x == 0)
            ((double*)(ws + OFF_NEGSUM))[row] =
                wr[0] + wr[1] + wr[2] + wr[3] +
                (double)rem * (double)softplus_f(unsortkey(Tkey));
    } else {
        // exactness fallback: stream full row (never taken on this data)
        for (int it = 0; it < 32; it++) {
            const unsigned mid = lo + ((hi - lo) >> 1);
            int c = 0;
            for (int i = threadIdx.x; i < D_; i += 256)
                if (rowt[i] <= 0 && sortkey(rowc[i]) > mid) c++;
            const int tot = blockSumI(c, shI);
            if ((long long)tot >= k) lo = mid; else hi = mid;
        }
        Tkey = hi;
        int c = 0;
        double acc = 0.0;
        for (int i = threadIdx.x; i < D_; i += 256) {
            if (rowt[i] <= 0) {
                float x = rowc[i];
                if (sortkey(x) > Tkey) { c++; acc += (double)softplus_f(x); }
            }
        }
        rem = (int)(k - (long long)blockSumI(c, shI));
        double t = wredD(acc);
        if (lane == 0) wr[wid] = t;
        __syncthreads();
        if (threadIdx.x == 0)
            ((double*)(ws + OFF_NEGSUM))[row] =
                wr[0] + wr[1] + wr[2] + wr[3] +
                (double)rem * (double)softplus_f(unsortkey(Tkey));
    }
}

// K5: reduce per-block partials -> two output scalars.
__global__ void __launch_bounds__(256)
mbl_k5(unsigned char* __restrict__ ws, float* __restrict__ out)
{
    __shared__ double wrA[4], wrB[4], wrC[4];
    __shared__ int shN[4], shK[4];
    const double* sl1p = (const double*)(ws + OFF_SL1P);
    const double* bcep = (const double*)(ws + OFF_BCEP);
    const unsigned* npb = (const unsigned*)(ws + OFF_NP);
    const int* ksel = (const int*)(ws + OFF_KSEL);
    const double* ns = (const double*)(ws + OFF_NEGSUM);

    double a = 0.0, b = 0.0, c = 0.0;
    int n = 0, kk = 0;
    for (int i = threadIdx.x; i < NBLK; i += 256) {
        a += sl1p[i]; b += bcep[i]; n += (int)npb[i];
    }
    if (threadIdx.x < 64) { kk = ksel[threadIdx.x]; c = ns[threadIdx.x]; }

    double ra = wredD(a), rb = wredD(b), rc = wredD(c);
    int rn = wredI(n), rk = wredI(kk);
    const int lane = threadIdx.x & 63, wid = threadIdx.x >> 6;
    if (lane == 0) { wrA[wid] = ra; wrB[wid] = rb; wrC[wid] = rc; shN[wid] = rn; shK[wid] = rk; }
    __syncthreads();
    if (threadIdx.x == 0) {
        double SL1 = wrA[0] + wrA[1] + wrA[2] + wrA[3];
        double BCE = wrB[0] + wrB[1] + wrB[2] + wrB[3];
        double NSUM = wrC[0] + wrC[1] + wrC[2] + wrC[3];
        double Np = (double)(shN[0] + shN[1] + shN[2] + shN[3]);
        double Kt = (double)(shK[0] + shK[1] + shK[2] + shK[3]);
        double out0 = (Np > 0.0) ? (SL1 / (4.0 * Np)) / Np : 0.0;
        double denom = Np + Kt;
        double out1 = (Np > 0.0 && denom > 0.0) ? ((BCE + NSUM) / denom) / Np : 0.0;
        out[0] = (float)out0;
        out[1] = (float)out1;
    }
}

extern "C" void kernel_launch(void* const* d_in, const int* in_sizes, int n_in,
                              void* d_out, int out_size, void* d_ws, size_t ws_size,
                              hipStream_t stream)
{
    const float4* loc4  = (const float4*)d_in[0];   // (B,D,4) f32
    const float*  conf  = (const float*)d_in[1];    // (B,D,1) f32
    const float4* loct4 = (const float4*)d_in[2];   // (B,D,4) f32
    const int*    conft = (const int*)d_in[3];      // (B,D)   i32
    unsigned char* ws = (unsigned char*)d_ws;
    float* out = (float*)d_out;

    mbl_k1<<<dim3(NBLK), dim3(256), 0, stream>>>(loc4, conf, loct4, conft, ws);
    mbl_ksel<<<dim3(B_), dim3(256), 0, stream>>>(conf, conft, ws);
    mbl_k5<<<dim3(1), dim3(256), 0, stream>>>(ws, out);
}

// Round 6
// 195.248 us; speedup vs baseline: 2.2846x; 1.0007x over previous
//
#include <hip/hip_runtime.h>
#include <stdint.h>

// MultiBoxLoss: B=64 rows, D=65536 anchors, ~2% positives.
// R6: ksel rebuilt — R5's 32-step binary search serialized 32 block-wide
// reductions (~1.3K cy each -> 43us). Now: one 4096-bin LINEAR-in-x LDS
// histogram (~1.7 cand/bin -> near-zero atomic conflict, unlike R3's
// exponent-bit bins), one thread-0 suffix scan, tiny rank-select inside the
// k-th bin (~10 elems, broadcast reads), ONE final block reduction for the
// exact fp64 top-k sum. ~8 barriers total instead of 64+.
// k1/k5 unchanged from R5 (per-block segments, no atomics, no memset).

#define B_ 64
#define D_ 65536
#define NEGPOS 3
#define BPR 16                 // blocks per row
#define NBLK (B_ * BPR)        // 1024
#define CHUNK (D_ / BPR)       // 4096 elements per block
#define XC 1.25f               // candidate cutoff (P(x>=XC)~10.6% per row)
#define CAPC 16384             // per-row candidate cap for non-fallback path
#define NREG 32                // register keys/thread (covers n<=8192)
#define HBINS 4096             // ksel histogram bins over x in [XC, XC+XRANGE)
#define XRANGE 5.0f
#define CJCAP 1024             // bin-J gather capacity (expect ~10)

// ---------------- ws layout (bytes), nothing needs zeroing ----------------
#define OFF_SL1P     0                      // double[NBLK]
#define OFF_BCEP     8192                   // double[NBLK]
#define OFF_NP       16384                  // u32[NBLK]
#define OFF_CC       20480                  // u32[NBLK]
#define OFF_NEGSUM   24576                  // double[64]
#define OFF_KSEL     25088                  // int[64]
#define OFF_CAND     32768                  // float[NBLK][CHUNK] = 16 MiB

__device__ __forceinline__ float softplus_f(float x) {   // bce for t=0
    return fmaxf(x, 0.0f) + log1pf(expf(-fabsf(x)));
}

__device__ __forceinline__ unsigned sortkey(float x) {   // uint order == float order
    unsigned u = __float_as_uint(x);
    return (u & 0x80000000u) ? ~u : (u | 0x80000000u);
}
__device__ __forceinline__ float unsortkey(unsigned s) {
    unsigned u = (s & 0x80000000u) ? (s & 0x7FFFFFFFu) : ~s;
    return __uint_as_float(u);
}

__device__ __forceinline__ int bin_of_x(float x) {
    int b = (int)((x - XC) * ((float)HBINS / XRANGE));
    return max(0, min(HBINS - 1, b));
}

__device__ __forceinline__ float smooth_l1_4(float4 a, float4 b) {
    float s = 0.0f, d, ad;
    d = a.x - b.x; ad = fabsf(d); s += (ad < 1.0f) ? 0.5f * d * d : ad - 0.5f;
    d = a.y - b.y; ad = fabsf(d); s += (ad < 1.0f) ? 0.5f * d * d : ad - 0.5f;
    d = a.z - b.z; ad = fabsf(d); s += (ad < 1.0f) ? 0.5f * d * d : ad - 0.5f;
    d = a.w - b.w; ad = fabsf(d); s += (ad < 1.0f) ? 0.5f * d * d : ad - 0.5f;
    return s;
}

__device__ __forceinline__ double wredD(double v) {
#pragma unroll
    for (int o = 32; o > 0; o >>= 1) v += __shfl_down(v, o, 64);
    return v;
}
__device__ __forceinline__ int wredI(int v) {
#pragma unroll
    for (int o = 32; o > 0; o >>= 1) v += __shfl_down(v, o, 64);
    return v;
}

// K1: one coalesced pass over conf+conft per 4096-elem chunk. (unchanged R5)
__global__ void __launch_bounds__(256)
mbl_k1(const float4* __restrict__ loc4, const float* __restrict__ conf,
       const float4* __restrict__ loct4, const int* __restrict__ conft,
       unsigned char* __restrict__ ws)
{
    __shared__ float lcand[CHUNK];
    __shared__ unsigned short lpos[CHUNK];
    __shared__ unsigned wtot[4];
    __shared__ double wr[8];

    const int block = blockIdx.x;
    const int base = block * CHUNK;
    const float4* c4 = (const float4*)(conf + base);
    const int4*   t4 = (const int4*)(conft + base);
    const int lane = threadIdx.x & 63, wid = threadIdx.x >> 6;

    float4 xv[4]; int4 tv[4];
#pragma unroll
    for (int it = 0; it < 4; it++) {
        const int g = threadIdx.x + it * 256;
        xv[it] = c4[g];
        tv[it] = t4[g];
    }

    double bcep = 0.0;
    unsigned cntc = 0, cntp = 0;
#pragma unroll
    for (int it = 0; it < 4; it++) {
#pragma unroll
        for (int c = 0; c < 4; c++) {
            float x = (c == 0) ? xv[it].x : (c == 1) ? xv[it].y : (c == 2) ? xv[it].z : xv[it].w;
            int   t = (c == 0) ? tv[it].x : (c == 1) ? tv[it].y : (c == 2) ? tv[it].z : tv[it].w;
            if (t > 0) { cntp++; bcep += (double)(softplus_f(x) - x); }
            else if (x >= XC) cntc++;
        }
    }

    unsigned pk = (cntc << 16) | cntp;
    unsigned incl = pk;
#pragma unroll
    for (int o = 1; o < 64; o <<= 1) {
        unsigned v = __shfl_up(incl, o, 64);
        if (lane >= o) incl += v;
    }
    unsigned excl = incl - pk;
    if (lane == 63) wtot[wid] = incl;
    __syncthreads();
    unsigned wbase = 0;
    for (int w = 0; w < wid; w++) wbase += wtot[w];
    const unsigned tot = wtot[0] + wtot[1] + wtot[2] + wtot[3];
    const unsigned totc = tot >> 16, totp = tot & 0xFFFFu;
    unsigned offc = (excl >> 16) + (wbase >> 16);
    unsigned offp = (excl & 0xFFFFu) + (wbase & 0xFFFFu);

#pragma unroll
    for (int it = 0; it < 4; it++) {
#pragma unroll
        for (int c = 0; c < 4; c++) {
            float x = (c == 0) ? xv[it].x : (c == 1) ? xv[it].y : (c == 2) ? xv[it].z : xv[it].w;
            int   t = (c == 0) ? tv[it].x : (c == 1) ? tv[it].y : (c == 2) ? tv[it].z : tv[it].w;
            const int li = (threadIdx.x + it * 256) * 4 + c;
            if (t > 0) lpos[offp++] = (unsigned short)li;
            else if (x >= XC) lcand[offc++] = x;
        }
    }
    __syncthreads();

    float* seg = (float*)(ws + OFF_CAND) + (size_t)block * CHUNK;
    for (unsigned i = threadIdx.x; i < totc; i += 256) seg[i] = lcand[i];

    double sl1 = 0.0;
    for (unsigned i = threadIdx.x; i < totp; i += 256) {
        const int e = base + (int)lpos[i];
        sl1 += (double)smooth_l1_4(loc4[e], loct4[e]);
    }

    double s1 = wredD(sl1), s2 = wredD(bcep);
    if (lane == 0) { wr[wid] = s1; wr[4 + wid] = s2; }
    __syncthreads();
    if (threadIdx.x == 0) {
        ((double*)(ws + OFF_SL1P))[block] = wr[0] + wr[1] + wr[2] + wr[3];
        ((double*)(ws + OFF_BCEP))[block] = wr[4] + wr[5] + wr[6] + wr[7];
        ((unsigned*)(ws + OFF_NP))[block] = totp;
        ((unsigned*)(ws + OFF_CC))[block] = totc;
    }
}

__device__ __forceinline__ int blockSumI(int v, int* sh) {
    int w = wredI(v);
    const int lane = threadIdx.x & 63, wid = threadIdx.x >> 6;
    __syncthreads();
    if (lane == 0) sh[wid] = w;
    __syncthreads();
    return sh[0] + sh[1] + sh[2] + sh[3];
}

// Ksel: one block per row; exact top-k sum via histogram select.
__global__ void __launch_bounds__(256)
mbl_ksel(const float* __restrict__ conf, const int* __restrict__ conft,
         unsigned char* __restrict__ ws)
{
    __shared__ unsigned segoff[BPR + 1];
    __shared__ unsigned hist[HBINS];     // 16 KB
    __shared__ unsigned part[256];
    __shared__ unsigned ubuf[CJCAP];     // bin-J keys
    __shared__ unsigned shJ, shRemJ, shCj, shT;
    __shared__ int shI[4];
    __shared__ double wr[4];

    const int row = blockIdx.x;
    const unsigned* cc = (const unsigned*)(ws + OFF_CC) + row * BPR;
    const unsigned* npb = (const unsigned*)(ws + OFF_NP) + row * BPR;

    if (threadIdx.x == 0) {
        unsigned o = 0;
        int np = 0;
#pragma unroll
        for (int s = 0; s < BPR; s++) { segoff[s] = o; o += cc[s]; np += (int)npb[s]; }
        segoff[BPR] = o;
        shI[0] = np;
    }
    __syncthreads();
    const int np = shI[0];
    const unsigned n = segoff[BPR];
    long long k = (long long)np * NEGPOS;
    if (k > D_) k = D_;
    long long negs = (long long)D_ - np;
    if (k > negs) k = negs;
    if (threadIdx.x == 0) ((int*)(ws + OFF_KSEL))[row] = (int)k;
    if (k <= 0) {
        if (threadIdx.x == 0) ((double*)(ws + OFF_NEGSUM))[row] = 0.0;
        return;
    }
    __syncthreads();

    const bool fb = ((long long)n < k) || (n > (unsigned)(NREG * 256)) ||
                    (n > (unsigned)CAPC);
    const float* cand = (const float*)(ws + OFF_CAND);
    const float* rowc = conf + row * D_;
    const int*   rowt = conft + row * D_;
    const int lane = threadIdx.x & 63, wid = threadIdx.x >> 6;
    unsigned Tkey;
    int rem;

    if (!fb) {
        // ---- load keys to registers (sentinel 0; real keys >= sortkey(XC) > 0)
        unsigned keys[NREG];
#pragma unroll
        for (int j = 0; j < NREG; j++) {
            const unsigned g = (unsigned)(j * 256) + threadIdx.x;
            unsigned key = 0u;
            if (g < n) {
                int s = 0;
#pragma unroll
                for (int st = 8; st > 0; st >>= 1)
                    if (s + st <= BPR && segoff[s + st] <= g) s += st;
                const unsigned idx = g - segoff[s];
                key = sortkey(cand[(size_t)(row * BPR + s) * CHUNK + idx]);
            }
            keys[j] = key;
        }

        // ---- 4096-bin histogram, linear in x (hot bin ~10 -> low conflict)
        for (int i = threadIdx.x; i < HBINS; i += 256) hist[i] = 0;
        __syncthreads();
#pragma unroll
        for (int j = 0; j < NREG; j++)
            if (keys[j]) atomicAdd(&hist[bin_of_x(unsortkey(keys[j]))], 1u);
        __syncthreads();

        // ---- suffix scan: find bin J holding the k-th largest, remJ needed
        {
            unsigned s = 0; const int b0 = threadIdx.x * 16;
#pragma unroll
            for (int i = 0; i < 16; i++) s += hist[b0 + i];
            part[threadIdx.x] = s;
        }
        __syncthreads();
        if (threadIdx.x == 0) {
            long long cum = 0; unsigned J = 0, remJ = 0;
            for (int t = 255; t >= 0; t--) {
                if (cum + (long long)part[t] >= k) {
                    for (int b = t * 16 + 15; b >= t * 16; b--) {
                        cum += hist[b];
                        if (cum >= k) {
                            J = (unsigned)b;
                            remJ = (unsigned)(k - (cum - (long long)hist[b]));
                            break;
                        }
                    }
                    break;
                }
                cum += part[t];
            }
            shJ = J; shRemJ = remJ; shCj = 0;
        }
        __syncthreads();
        const unsigned J = shJ, remJ = shRemJ;

        // ---- gather bin-J keys (expected ~10)
#pragma unroll
        for (int j = 0; j < NREG; j++) {
            if (keys[j] && (unsigned)bin_of_x(unsortkey(keys[j])) == J) {
                unsigned p = atomicAdd(&shCj, 1u);
                if (p < CJCAP) ubuf[p] = keys[j];
            }
        }
        __syncthreads();
        const unsigned cj = shCj;

        if (cj <= CJCAP) {
            // rank select: element with cntGT < remJ <= cntGT+cntEQ is the
            // remJ-th largest VALUE in bin J (all writers share one value).
            for (unsigned i = threadIdx.x; i < cj; i += 256) {
                const unsigned ki = ubuf[i];
                unsigned gt = 0, ge = 0;
                for (unsigned l = 0; l < cj; l++) {     // broadcast reads
                    const unsigned kl = ubuf[l];
                    gt += (kl > ki) ? 1u : 0u;
                    ge += (kl >= ki) ? 1u : 0u;
                }
                if (gt < remJ && ge >= remJ) shT = ki;
            }
            __syncthreads();
            Tkey = shT;
        } else {
            // pathological (mass tie): 32-step block binary search, exact
            unsigned lo = 0u, hi = 0xFFFFFFFFu;
            for (int it = 0; it < 32; it++) {
                const unsigned mid = lo + ((hi - lo) >> 1);
                int c = 0;
#pragma unroll
                for (int j = 0; j < NREG; j++) c += (keys[j] > mid) ? 1 : 0;
                const int tot = blockSumI(c, shI);
                if ((long long)tot >= k) lo = mid; else hi = mid;
            }
            Tkey = hi;
        }

        // ---- one final reduction: exact fp64 top-k sum
        int c = 0;
        double acc = 0.0;
#pragma unroll
        for (int j = 0; j < NREG; j++) {
            if (keys[j] > Tkey) { c++; acc += (double)softplus_f(unsortkey(keys[j])); }
        }
        const int tot = blockSumI(c, shI);
        rem = (int)(k - (long long)tot);
        double t = wredD(acc);
        if (lane == 0) wr[wid] = t;
        __syncthreads();
        if (threadIdx.x == 0)
            ((double*)(ws + OFF_NEGSUM))[row] =
                wr[0] + wr[1] + wr[2] + wr[3] +
                (double)rem * (double)softplus_f(unsortkey(Tkey));
    } else {
        // exactness fallback: stream full row (never taken on this data)
        unsigned lo = 0u, hi = 0xFFFFFFFFu;
        for (int it = 0; it < 32; it++) {
            const unsigned mid = lo + ((hi - lo) >> 1);
            int c = 0;
            for (int i = threadIdx.x; i < D_; i += 256)
                if (rowt[i] <= 0 && sortkey(rowc[i]) > mid) c++;
            const int tot = blockSumI(c, shI);
            if ((long long)tot >= k) lo = mid; else hi = mid;
        }
        Tkey = hi;
        int c = 0;
        double acc = 0.0;
        for (int i = threadIdx.x; i < D_; i += 256) {
            if (rowt[i] <= 0) {
                float x = rowc[i];
                if (sortkey(x) > Tkey) { c++; acc += (double)softplus_f(x); }
            }
        }
        rem = (int)(k - (long long)blockSumI(c, shI));
        double t = wredD(acc);
        if (lane == 0) wr[wid] = t;
        __syncthreads();
        if (threadIdx.x == 0)
            ((double*)(ws + OFF_NEGSUM))[row] =
                wr[0] + wr[1] + wr[2] + wr[3] +
                (double)rem * (double)softplus_f(unsortkey(Tkey));
    }
}

// K5: reduce per-block partials -> two output scalars. (unchanged R5)
__global__ void __launch_bounds__(256)
mbl_k5(unsigned char* __restrict__ ws, float* __restrict__ out)
{
    __shared__ double wrA[4], wrB[4], wrC[4];
    __shared__ int shN[4], shK[4];
    const double* sl1p = (const double*)(ws + OFF_SL1P);
    const double* bcep = (const double*)(ws + OFF_BCEP);
    const unsigned* npb = (const unsigned*)(ws + OFF_NP);
    const int* ksel = (const int*)(ws + OFF_KSEL);
    const double* ns = (const double*)(ws + OFF_NEGSUM);

    double a = 0.0, b = 0.0, c = 0.0;
    int n = 0, kk = 0;
    for (int i = threadIdx.x; i < NBLK; i += 256) {
        a += sl1p[i]; b += bcep[i]; n += (int)npb[i];
    }
    if (threadIdx.x < 64) { kk = ksel[threadIdx.x]; c = ns[threadIdx.x]; }

    double ra = wredD(a), rb = wredD(b), rc = wredD(c);
    int rn = wredI(n), rk = wredI(kk);
    const int lane = threadIdx.x & 63, wid = threadIdx.x >> 6;
    if (lane == 0) { wrA[wid] = ra; wrB[wid] = rb; wrC[wid] = rc; shN[wid] = rn; shK[wid] = rk; }
    __syncthreads();
    if (threadIdx.x == 0) {
        double SL1 = wrA[0] + wrA[1] + wrA[2] + wrA[3];
        double BCE = wrB[0] + wrB[1] + wrB[2] + wrB[3];
        double NSUM = wrC[0] + wrC[1] + wrC[2] + wrC[3];
        double Np = (double)(shN[0] + shN[1] + shN[2] + shN[3]);
        double Kt = (double)(shK[0] + shK[1] + shK[2] + shK[3]);
        double out0 = (Np > 0.0) ? (SL1 / (4.0 * Np)) / Np : 0.0;
        double denom = Np + Kt;
        double out1 = (Np > 0.0 && denom > 0.0) ? ((BCE + NSUM) / denom) / Np : 0.0;
        out[0] = (float)out0;
        out[1] = (float)out1;
    }
}

extern "C" void kernel_launch(void* const* d_in, const int* in_sizes, int n_in,
                              void* d_out, int out_size, void* d_ws, size_t ws_size,
                              hipStream_t stream)
{
    const float4* loc4  = (const float4*)d_in[0];   // (B,D,4) f32
    const float*  conf  = (const float*)d_in[1];    // (B,D,1) f32
    const float4* loct4 = (const float4*)d_in[2];   // (B,D,4) f32
    const int*    conft = (const int*)d_in[3];      // (B,D)   i32
    unsigned char* ws = (unsigned char*)d_ws;
    float* out = (float*)d_out;

    mbl_k1<<<dim3(NBLK), dim3(256), 0, stream>>>(loc4, conf, loct4, conft, ws);
    mbl_ksel<<<dim3(B_), dim3(256), 0, stream>>>(conf, conft, ws);
    mbl_k5<<<dim3(1), dim3(256), 0, stream>>>(ws, out);
}

// Round 7
// 174.829 us; speedup vs baseline: 2.5515x; 1.1168x over previous
//
#include <hip/hip_runtime.h>
#include <stdint.h>

// MultiBoxLoss: B=64 rows, D=65536 anchors, ~2% positives.
// R7: ksel latency rebuild. R6 was still 42us: with 64 blocks there is no
// TLP, and two O(100+) serial dependent chains dominated — the thread-0
// suffix scan (~235 serial LDS reads) and the per-key segment binary search
// (32 x 4-deep LDS chains). Now: candidates staged flat into LDS via a
// direct segment->16-thread mapping, PARALLEL block suffix scan over the
// 4096-bin histogram, wave-0 shfl scan for segment offsets. Longest serial
// chain left is ~16 LDS reads (crossing thread walks its 16 bins).
// k1/k5 unchanged from R5.

#define B_ 64
#define D_ 65536
#define NEGPOS 3
#define BPR 16                 // blocks per row
#define NBLK (B_ * BPR)        // 1024
#define CHUNK (D_ / BPR)       // 4096 elements per block
#define XC 1.25f               // candidate cutoff (P(x>=XC)~10.6% per row)
#define LCAP 8192              // ksel LDS candidate capacity (n~6900, 16 sigma)
#define HBINS 4096             // histogram bins over x in [XC, XC+XRANGE)
#define XRANGE 5.0f
#define CJCAP 1024             // bin-J gather capacity (expect ~8)

// ---------------- ws layout (bytes), nothing needs zeroing ----------------
#define OFF_SL1P     0                      // double[NBLK]
#define OFF_BCEP     8192                   // double[NBLK]
#define OFF_NP       16384                  // u32[NBLK]
#define OFF_CC       20480                  // u32[NBLK]
#define OFF_NEGSUM   24576                  // double[64]
#define OFF_KSEL     25088                  // int[64]
#define OFF_CAND     32768                  // float[NBLK][CHUNK] = 16 MiB

__device__ __forceinline__ float softplus_f(float x) {   // bce for t=0
    return fmaxf(x, 0.0f) + log1pf(expf(-fabsf(x)));
}

__device__ __forceinline__ int bin_of_x(float x) {
    int b = (int)((x - XC) * ((float)HBINS / XRANGE));
    return max(0, min(HBINS - 1, b));
}

__device__ __forceinline__ float smooth_l1_4(float4 a, float4 b) {
    float s = 0.0f, d, ad;
    d = a.x - b.x; ad = fabsf(d); s += (ad < 1.0f) ? 0.5f * d * d : ad - 0.5f;
    d = a.y - b.y; ad = fabsf(d); s += (ad < 1.0f) ? 0.5f * d * d : ad - 0.5f;
    d = a.z - b.z; ad = fabsf(d); s += (ad < 1.0f) ? 0.5f * d * d : ad - 0.5f;
    d = a.w - b.w; ad = fabsf(d); s += (ad < 1.0f) ? 0.5f * d * d : ad - 0.5f;
    return s;
}

__device__ __forceinline__ double wredD(double v) {
#pragma unroll
    for (int o = 32; o > 0; o >>= 1) v += __shfl_down(v, o, 64);
    return v;
}
__device__ __forceinline__ int wredI(int v) {
#pragma unroll
    for (int o = 32; o > 0; o >>= 1) v += __shfl_down(v, o, 64);
    return v;
}

// K1: one coalesced pass over conf+conft per 4096-elem chunk. (unchanged R5)
__global__ void __launch_bounds__(256)
mbl_k1(const float4* __restrict__ loc4, const float* __restrict__ conf,
       const float4* __restrict__ loct4, const int* __restrict__ conft,
       unsigned char* __restrict__ ws)
{
    __shared__ float lcand[CHUNK];
    __shared__ unsigned short lpos[CHUNK];
    __shared__ unsigned wtot[4];
    __shared__ double wr[8];

    const int block = blockIdx.x;
    const int base = block * CHUNK;
    const float4* c4 = (const float4*)(conf + base);
    const int4*   t4 = (const int4*)(conft + base);
    const int lane = threadIdx.x & 63, wid = threadIdx.x >> 6;

    float4 xv[4]; int4 tv[4];
#pragma unroll
    for (int it = 0; it < 4; it++) {
        const int g = threadIdx.x + it * 256;
        xv[it] = c4[g];
        tv[it] = t4[g];
    }

    double bcep = 0.0;
    unsigned cntc = 0, cntp = 0;
#pragma unroll
    for (int it = 0; it < 4; it++) {
#pragma unroll
        for (int c = 0; c < 4; c++) {
            float x = (c == 0) ? xv[it].x : (c == 1) ? xv[it].y : (c == 2) ? xv[it].z : xv[it].w;
            int   t = (c == 0) ? tv[it].x : (c == 1) ? tv[it].y : (c == 2) ? tv[it].z : tv[it].w;
            if (t > 0) { cntp++; bcep += (double)(softplus_f(x) - x); }
            else if (x >= XC) cntc++;
        }
    }

    unsigned pk = (cntc << 16) | cntp;
    unsigned incl = pk;
#pragma unroll
    for (int o = 1; o < 64; o <<= 1) {
        unsigned v = __shfl_up(incl, o, 64);
        if (lane >= o) incl += v;
    }
    unsigned excl = incl - pk;
    if (lane == 63) wtot[wid] = incl;
    __syncthreads();
    unsigned wbase = 0;
    for (int w = 0; w < wid; w++) wbase += wtot[w];
    const unsigned tot = wtot[0] + wtot[1] + wtot[2] + wtot[3];
    const unsigned totc = tot >> 16, totp = tot & 0xFFFFu;
    unsigned offc = (excl >> 16) + (wbase >> 16);
    unsigned offp = (excl & 0xFFFFu) + (wbase & 0xFFFFu);

#pragma unroll
    for (int it = 0; it < 4; it++) {
#pragma unroll
        for (int c = 0; c < 4; c++) {
            float x = (c == 0) ? xv[it].x : (c == 1) ? xv[it].y : (c == 2) ? xv[it].z : xv[it].w;
            int   t = (c == 0) ? tv[it].x : (c == 1) ? tv[it].y : (c == 2) ? tv[it].z : tv[it].w;
            const int li = (threadIdx.x + it * 256) * 4 + c;
            if (t > 0) lpos[offp++] = (unsigned short)li;
            else if (x >= XC) lcand[offc++] = x;
        }
    }
    __syncthreads();

    float* seg = (float*)(ws + OFF_CAND) + (size_t)block * CHUNK;
    for (unsigned i = threadIdx.x; i < totc; i += 256) seg[i] = lcand[i];

    double sl1 = 0.0;
    for (unsigned i = threadIdx.x; i < totp; i += 256) {
        const int e = base + (int)lpos[i];
        sl1 += (double)smooth_l1_4(loc4[e], loct4[e]);
    }

    double s1 = wredD(sl1), s2 = wredD(bcep);
    if (lane == 0) { wr[wid] = s1; wr[4 + wid] = s2; }
    __syncthreads();
    if (threadIdx.x == 0) {
        ((double*)(ws + OFF_SL1P))[block] = wr[0] + wr[1] + wr[2] + wr[3];
        ((double*)(ws + OFF_BCEP))[block] = wr[4] + wr[5] + wr[6] + wr[7];
        ((unsigned*)(ws + OFF_NP))[block] = totp;
        ((unsigned*)(ws + OFF_CC))[block] = totc;
    }
}

__device__ __forceinline__ int blockSumI(int v, int* sh) {
    int w = wredI(v);
    const int lane = threadIdx.x & 63, wid = threadIdx.x >> 6;
    __syncthreads();
    if (lane == 0) sh[wid] = w;
    __syncthreads();
    return sh[0] + sh[1] + sh[2] + sh[3];
}

// Ksel: one block per row; exact top-k softplus sum, all phases parallel.
__global__ void __launch_bounds__(256)
mbl_ksel(const float* __restrict__ conf, const int* __restrict__ conft,
         unsigned char* __restrict__ ws)
{
    __shared__ float lval[LCAP];         // 32 KB: candidates, flat
    __shared__ unsigned hist[HBINS];     // 16 KB
    __shared__ unsigned part[256];
    __shared__ unsigned ubuf[CJCAP];
    __shared__ unsigned segoff[BPR + 1];
    __shared__ unsigned scc[BPR];
    __shared__ unsigned wsuf[4];
    __shared__ unsigned shJ, shRemJ, shCj, shNP;
    __shared__ float shXT;
    __shared__ int shI[4];
    __shared__ double wr[4];

    const int row = blockIdx.x;
    const unsigned* cc = (const unsigned*)(ws + OFF_CC) + row * BPR;
    const unsigned* npb = (const unsigned*)(ws + OFF_NP) + row * BPR;
    const int lane = threadIdx.x & 63, wid = threadIdx.x >> 6;

    // ---- wave-0 shfl prefix scan of the 16 segment counts + np sum
    if (wid == 0) {
        unsigned c = (lane < BPR) ? cc[lane] : 0u;
        unsigned p = (lane < BPR) ? npb[lane] : 0u;
        unsigned inc = c;
#pragma unroll
        for (int o = 1; o < BPR; o <<= 1) {
            unsigned v = __shfl_up(inc, o, 64);
            if (lane >= o) inc += v;
        }
        unsigned ptot = p;
#pragma unroll
        for (int o = 1; o < BPR; o <<= 1) ptot += __shfl_down(ptot, o, 64);
        if (lane < BPR) { segoff[lane] = inc - c; scc[lane] = c; }
        if (lane == BPR - 1) segoff[BPR] = inc;
        if (lane == 0) { shNP = ptot; shCj = 0; }
    }
    __syncthreads();

    const int np = (int)shNP;
    const unsigned n = segoff[BPR];
    long long k = (long long)np * NEGPOS;
    if (k > D_) k = D_;
    long long negs = (long long)D_ - np;
    if (k > negs) k = negs;
    if (threadIdx.x == 0) ((int*)(ws + OFF_KSEL))[row] = (int)k;
    if (k <= 0) {
        if (threadIdx.x == 0) ((double*)(ws + OFF_NEGSUM))[row] = 0.0;
        return;
    }

    const float* cand = (const float*)(ws + OFF_CAND);
    const float* rowc = conf + row * D_;
    const int*   rowt = conft + row * D_;
    const bool fb = ((long long)n < k) || (n > (unsigned)LCAP);
    float xT;
    int rem;

    if (!fb) {
        // ---- stage candidates into LDS: 16 threads per segment, no search
        {
            const int s = threadIdx.x >> 4, li = threadIdx.x & 15;
            const float* gseg = cand + (size_t)(row * BPR + s) * CHUNK;
            const unsigned cs = scc[s], d0 = segoff[s];
            for (unsigned i = li; i < cs; i += 16) lval[d0 + i] = gseg[i];
        }
        // ---- zero + build histogram (linear in x; hot bin ~8)
        for (int i = threadIdx.x; i < HBINS; i += 256) hist[i] = 0;
        __syncthreads();
        for (unsigned i = threadIdx.x; i < n; i += 256)
            atomicAdd(&hist[bin_of_x(lval[i])], 1u);
        __syncthreads();

        // ---- parallel suffix scan: part[t] = sum of chunk t (16 bins)
        {
            unsigned s = 0; const int b0 = threadIdx.x * 16;
#pragma unroll
            for (int i = 0; i < 16; i++) s += hist[b0 + i];
            part[threadIdx.x] = s;
            // inclusive suffix within wave
            unsigned suf = s;
#pragma unroll
            for (int o = 1; o < 64; o <<= 1) {
                unsigned v = __shfl_down(suf, o, 64);
                if (lane + o < 64) suf += v;
            }
            if (lane == 0) wsuf[wid] = suf;
            __syncthreads();
            unsigned add = 0;
            for (int w = wid + 1; w < 4; w++) add += wsuf[w];
            suf += add;                         // inclusive suffix over all 256
            const unsigned sufx = suf - s;      // bins strictly above my chunk
            if ((long long)sufx < k && (long long)suf >= k) {
                // crossing is in my 16 bins: walk them (<=16 serial reads)
                long long cum = sufx;
                for (int b = threadIdx.x * 16 + 15; b >= threadIdx.x * 16; b--) {
                    cum += hist[b];
                    if (cum >= k) {
                        shJ = (unsigned)b;
                        shRemJ = (unsigned)(k - (cum - (long long)hist[b]));
                        break;
                    }
                }
            }
        }
        __syncthreads();
        const unsigned J = shJ, remJ = shRemJ;

        // ---- gather bin-J values (expected ~8)
        for (unsigned i = threadIdx.x; i < n; i += 256) {
            float x = lval[i];
            if ((unsigned)bin_of_x(x) == J) {
                unsigned p = atomicAdd(&shCj, 1u);
                if (p < CJCAP) ubuf[p] = __float_as_uint(x);
            }
        }
        __syncthreads();
        const unsigned cj = shCj;

        if (cj <= CJCAP) {
            // rank select the remJ-th largest value in bin J (all x > 0 ->
            // float compare == value order; exact, deterministic)
            for (unsigned i = threadIdx.x; i < cj; i += 256) {
                const float xi = __uint_as_float(ubuf[i]);
                unsigned gt = 0, ge = 0;
                for (unsigned l = 0; l < cj; l++) {
                    const float xl = __uint_as_float(ubuf[l]);
                    gt += (xl > xi) ? 1u : 0u;
                    ge += (xl >= xi) ? 1u : 0u;
                }
                if (gt < remJ && ge >= remJ) shXT = xi;
            }
            __syncthreads();
            xT = shXT;
        } else {
            // pathological mass-tie: 22-step value binary search over LDS
            float flo = XC - 1.0f, fhi = XC + XRANGE + 1.0f;
            for (int it = 0; it < 40; it++) {
                const float mid = 0.5f * (flo + fhi);
                int c = 0;
                for (unsigned i = threadIdx.x; i < n; i += 256)
                    if (lval[i] > mid) c++;
                const int tot = blockSumI(c, shI);
                if ((long long)tot >= k) flo = mid; else fhi = mid;
                if (!(flo < fhi)) break;
            }
            // fhi is the smallest value with count(>fhi) < k — walk to the
            // exact float: take min value strictly greater than flo
            // (simpler: use fhi as threshold after convergence)
            xT = fhi;
        }

        // ---- final exact fp64 top-k sum
        int c = 0;
        double acc = 0.0;
        for (unsigned i = threadIdx.x; i < n; i += 256) {
            float x = lval[i];
            if (x > xT) { c++; acc += (double)softplus_f(x); }
        }
        const int tot = blockSumI(c, shI);
        rem = (int)(k - (long long)tot);
        double t = wredD(acc);
        if (lane == 0) wr[wid] = t;
        __syncthreads();
        if (threadIdx.x == 0)
            ((double*)(ws + OFF_NEGSUM))[row] =
                wr[0] + wr[1] + wr[2] + wr[3] +
                (double)rem * (double)softplus_f(xT);
    } else {
        // exactness fallback: value binary search over full row (bit-exact
        // via uint bisection on positive-float keys is overkill here; use
        // 64-step float bisection then exact tie handling by count)
        // Bit-exact approach: bisect on uint of x for x>0; for x<=0 keys
        // impossible to be in top-k when k<=negs only if ... keep general:
        // bisect on sortable uint.
        unsigned lo = 0u, hi = 0xFFFFFFFFu;
        for (int it = 0; it < 32; it++) {
            const unsigned mid = lo + ((hi - lo) >> 1);
            // sortable uint -> float for compare
            unsigned um = (mid & 0x80000000u) ? (mid & 0x7FFFFFFFu) : ~mid;
            float fm = __uint_as_float(um);
            int c = 0;
            for (int i = threadIdx.x; i < D_; i += 256)
                if (rowt[i] <= 0 && rowc[i] > fm) c++;
            const int tot = blockSumI(c, shI);
            if ((long long)tot >= k) lo = mid; else hi = mid;
        }
        unsigned uT = (hi & 0x80000000u) ? (hi & 0x7FFFFFFFu) : ~hi;
        xT = __uint_as_float(uT);
        int c = 0;
        double acc = 0.0;
        for (int i = threadIdx.x; i < D_; i += 256) {
            if (rowt[i] <= 0) {
                float x = rowc[i];
                if (x > xT) { c++; acc += (double)softplus_f(x); }
            }
        }
        rem = (int)(k - (long long)blockSumI(c, shI));
        double t = wredD(acc);
        if (lane == 0) wr[wid] = t;
        __syncthreads();
        if (threadIdx.x == 0)
            ((double*)(ws + OFF_NEGSUM))[row] =
                wr[0] + wr[1] + wr[2] + wr[3] +
                (double)rem * (double)softplus_f(xT);
    }
}

// K5: reduce per-block partials -> two output scalars. (unchanged R5)
__global__ void __launch_bounds__(256)
mbl_k5(unsigned char* __restrict__ ws, float* __restrict__ out)
{
    __shared__ double wrA[4], wrB[4], wrC[4];
    __shared__ int shN[4], shK[4];
    const double* sl1p = (const double*)(ws + OFF_SL1P);
    const double* bcep = (const double*)(ws + OFF_BCEP);
    const unsigned* npb = (const unsigned*)(ws + OFF_NP);
    const int* ksel = (const int*)(ws + OFF_KSEL);
    const double* ns = (const double*)(ws + OFF_NEGSUM);

    double a = 0.0, b = 0.0, c = 0.0;
    int n = 0, kk = 0;
    for (int i = threadIdx.x; i < NBLK; i += 256) {
        a += sl1p[i]; b += bcep[i]; n += (int)npb[i];
    }
    if (threadIdx.x < 64) { kk = ksel[threadIdx.x]; c = ns[threadIdx.x]; }

    double ra = wredD(a), rb = wredD(b), rc = wredD(c);
    int rn = wredI(n), rk = wredI(kk);
    const int lane = threadIdx.x & 63, wid = threadIdx.x >> 6;
    if (lane == 0) { wrA[wid] = ra; wrB[wid] = rb; wrC[wid] = rc; shN[wid] = rn; shK[wid] = rk; }
    __syncthreads();
    if (threadIdx.x == 0) {
        double SL1 = wrA[0] + wrA[1] + wrA[2] + wrA[3];
        double BCE = wrB[0] + wrB[1] + wrB[2] + wrB[3];
        double NSUM = wrC[0] + wrC[1] + wrC[2] + wrC[3];
        double Np = (double)(shN[0] + shN[1] + shN[2] + shN[3]);
        double Kt = (double)(shK[0] + shK[1] + shK[2] + shK[3]);
        double out0 = (Np > 0.0) ? (SL1 / (4.0 * Np)) / Np : 0.0;
        double denom = Np + Kt;
        double out1 = (Np > 0.0 && denom > 0.0) ? ((BCE + NSUM) / denom) / Np : 0.0;
        out[0] = (float)out0;
        out[1] = (float)out1;
    }
}

extern "C" void kernel_launch(void* const* d_in, const int* in_sizes, int n_in,
                              void* d_out, int out_size, void* d_ws, size_t ws_size,
                              hipStream_t stream)
{
    const float4* loc4  = (const float4*)d_in[0];   // (B,D,4) f32
    const float*  conf  = (const float*)d_in[1];    // (B,D,1) f32
    const float4* loct4 = (const float4*)d_in[2];   // (B,D,4) f32
    const int*    conft = (const int*)d_in[3];      // (B,D)   i32
    unsigned char* ws = (unsigned char*)d_ws;
    float* out = (float*)d_out;

    mbl_k1<<<dim3(NBLK), dim3(256), 0, stream>>>(loc4, conf, loct4, conft, ws);
    mbl_ksel<<<dim3(B_), dim3(256), 0, stream>>>(conf, conft, ws);
    mbl_k5<<<dim3(1), dim3(256), 0, stream>>>(ws, out);
}